// Round 7
// baseline (239.492 us; speedup 1.0000x reference)
//
#include <hip/hip_runtime.h>
#include <hip/hip_bf16.h>

// Problem constants
#define NN    16384      // N nodes
#define EE    262144     // edges
#define BNODES 32768     // B*N
#define AH    384        // A*H
#define TOT_NOISE 1572864u

typedef __attribute__((ext_vector_type(8))) short short8;
typedef __attribute__((ext_vector_type(4))) float v4f;
typedef __attribute__((ext_vector_type(2))) float f32x2;

__device__ __forceinline__ unsigned short f2bf(float f) {
  unsigned u = __float_as_uint(f);
  unsigned r = u + 0x7fffu + ((u >> 16) & 1u);
  return (unsigned short)(r >> 16);
}
__device__ __forceinline__ float bf2f(unsigned short h) {
  return __uint_as_float(((unsigned)h) << 16);
}
__device__ __forceinline__ float bflo(unsigned u) { return __uint_as_float(u << 16); }
__device__ __forceinline__ float bfhi(unsigned u) { return __uint_as_float(u & 0xffff0000u); }
// HW packed fp32x2 -> bf16x2 (v_cvt_pk_bf16_f32, RNE — identical to f2bf)
__device__ __forceinline__ unsigned pk_bf16(float a, float b) {
  __hip_bfloat162 h = __float22bfloat162_rn(make_float2(a, b));
  return *(unsigned*)&h;
}

// ---------------------------------------------------------------------------
// Threefry-2x32, keys = (0, 42)
// ---------------------------------------------------------------------------
__device__ __forceinline__ void threefry2x32_042(unsigned& x0, unsigned& x1) {
  const unsigned ks0 = 0u;
  const unsigned ks1 = 42u;
  const unsigned ks2 = 0x1BD11BDAu ^ 0u ^ 42u;
  x0 += ks0; x1 += ks1;
#define TFR(r) { x0 += x1; x1 = (x1 << (r)) | (x1 >> (32 - (r))); x1 ^= x0; }
  TFR(13) TFR(15) TFR(26) TFR(6)   x0 += ks1; x1 += ks2 + 1u;
  TFR(17) TFR(29) TFR(16) TFR(24)  x0 += ks2; x1 += ks0 + 2u;
  TFR(13) TFR(15) TFR(26) TFR(6)   x0 += ks0; x1 += ks1 + 3u;
  TFR(17) TFR(29) TFR(16) TFR(24)  x0 += ks1; x1 += ks2 + 4u;
  TFR(13) TFR(15) TFR(26) TFR(6)   x0 += ks2; x1 += ks0 + 5u;
#undef TFR
}

// XLA ErfInv32 (Giles) polynomial
__device__ __forceinline__ float erfinv_f32(float x) {
  float w = -log1pf(-x * x);
  float p;
  if (w < 5.0f) {
    w -= 2.5f;
    p = 2.81022636e-08f;
    p = fmaf(p, w, 3.43273939e-07f);
    p = fmaf(p, w, -3.5233877e-06f);
    p = fmaf(p, w, -4.39150654e-06f);
    p = fmaf(p, w, 0.00021858087f);
    p = fmaf(p, w, -0.00125372503f);
    p = fmaf(p, w, -0.00417768164f);
    p = fmaf(p, w, 0.246640727f);
    p = fmaf(p, w, 1.50140941f);
  } else {
    w = sqrtf(w) - 3.0f;
    p = -0.000200214257f;
    p = fmaf(p, w, 0.000100950558f);
    p = fmaf(p, w, 0.00134934322f);
    p = fmaf(p, w, -0.00367342844f);
    p = fmaf(p, w, 0.00573950773f);
    p = fmaf(p, w, -0.0076224613f);
    p = fmaf(p, w, 0.00943887047f);
    p = fmaf(p, w, 1.00167406f);
    p = fmaf(p, w, 2.83297682f);
  }
  return p * x;
}

__device__ __forceinline__ unsigned jax_random_bits32(unsigned i) {
  unsigned x0 = 0u, x1 = i;
  threefry2x32_042(x0, x1);
  return x0 ^ x1;
}

__device__ __forceinline__ float jax_normal_from_bits(unsigned bits) {
  float f = __uint_as_float((bits >> 9) | 0x3f800000u) - 1.0f;  // [0,1)
  const float lo = -0.99999994f;                                 // nextafter(-1,0)
  float u = f * 2.0f + lo;
  u = fmaxf(u, lo);
  return 1.4142135623730951f * erfinv_f32(u);
}

// ---------------------------------------------------------------------------
// CSR build
// ---------------------------------------------------------------------------
__global__ void edge_count(const int* __restrict__ dst, int* __restrict__ deg) {
  int e = blockIdx.x * 256 + threadIdx.x;
  if (e < EE) atomicAdd(&deg[dst[e]], 1);
}

__global__ __launch_bounds__(1024) void scan_k(const int* __restrict__ deg,
                                               int* __restrict__ offs,
                                               int* __restrict__ cur) {
  __shared__ int wsum[16];
  const int t = threadIdx.x;
  const int base = t * 16;
  int loc[16];
  int s = 0;
#pragma unroll
  for (int i = 0; i < 16; i++) { loc[i] = deg[base + i]; s += loc[i]; }
  const int mysum = s;
  const int lane = t & 63, wid = t >> 6;
#pragma unroll
  for (int off = 1; off < 64; off <<= 1) {
    int v = __shfl_up(s, off, 64);
    if (lane >= off) s += v;
  }
  if (lane == 63) wsum[wid] = s;
  __syncthreads();
  if (t == 0) {
    int r = 0;
#pragma unroll
    for (int i = 0; i < 16; i++) { int v = wsum[i]; wsum[i] = r; r += v; }
  }
  __syncthreads();
  int run = wsum[wid] + s - mysum;
#pragma unroll
  for (int i = 0; i < 16; i++) {
    offs[base + i] = run;
    cur[base + i] = run;
    run += loc[i];
  }
  if (t == 1023) offs[NN] = run;
}

__global__ void edge_fill(const int* __restrict__ dst, const int* __restrict__ srcv,
                          int* __restrict__ cur, int* __restrict__ csr) {
  int e = blockIdx.x * 256 + threadIdx.x;
  if (e < EE) {
    int d = dst[e];
    int p = atomicAdd(&cur[d], 1);
    csr[p] = srcv[e];
  }
}

// ---------------------------------------------------------------------------
// Weight prep: slots 0-2: W1[a]; 3-5: W2[a]; 6-8: mu_W1[a]; 9:Wq 10:Wk 11:Wv
// 12:Wo  (each 16384)  |  slot 13 region: mu_W2 fragments (3 x 2048)
// ---------------------------------------------------------------------------
__global__ __launch_bounds__(256) void prep_wfrag(
    const float* __restrict__ W1, const float* __restrict__ W2,
    const float* __restrict__ mW1,
    const float* __restrict__ Wq, const float* __restrict__ Wk,
    const float* __restrict__ Wv, const float* __restrict__ Wo,
    const float* __restrict__ mW2,
    unsigned short* __restrict__ F) {
  int m = blockIdx.y;
  int f = blockIdx.x * 256 + threadIdx.x;
  if (m == 13) {   // mu_W2: A x 128 x 16
    if (f < 6144) {
      int a = f >> 11;
      int r2 = f & 2047;
      int kt = r2 >> 9;
      int r = r2 & 511;
      int lane = r >> 3, j = r & 7;
      int k = kt * 32 + (lane >> 4) * 8 + j;
      int n = lane & 15;
      F[13 * 16384 + f] = f2bf(mW2[(a * 128 + k) * 16 + n]);
    }
    return;
  }
  const float* W;
  if (m < 3) W = W1 + (long)m * 16384;
  else if (m < 6) W = W2 + (long)(m - 3) * 16384;
  else if (m < 9) W = mW1 + (long)(m - 6) * 16384;
  else W = (m == 9) ? Wq : (m == 10) ? Wk : (m == 11) ? Wv : Wo;
  int tile = f >> 9;
  int kt = tile >> 3, nt = tile & 7;
  int r = f & 511;
  int lane = r >> 3, j = r & 7;
  int k = kt * 32 + (lane >> 4) * 8 + j;
  int n = nt * 16 + (lane & 15);
  F[(long)m * 16384 + f] = f2bf(W[k * 128 + n]);
}

// ---------------------------------------------------------------------------
// Fused 2-layer MLP: h = relu(x@W1+b1)@W2 + b2, per a. 128-row tiles.
// ---------------------------------------------------------------------------
#define GXSTR 136
__global__ __launch_bounds__(256, 4) void mlp_fused(
    const float* __restrict__ X,
    const unsigned short* __restrict__ WF1, const float* __restrict__ b1,
    const unsigned short* __restrict__ WF2, const float* __restrict__ b2,
    unsigned short* __restrict__ H) {
  __shared__ __align__(16) unsigned short As[128 * GXSTR];
  const int a = blockIdx.y;
  const long m0 = (long)blockIdx.x * 128;
  const int tid = threadIdx.x;
  const unsigned short* Wp1 = WF1 + (long)a * 16384;
  const unsigned short* Wp2 = WF2 + (long)a * 16384;

  // stage x tile fp32 -> bf16 (HW packed convert)
#pragma unroll
  for (int p = 0; p < 8; p++) {
    int c = tid + p * 256;
    int row = c >> 4, c8 = (c & 15) * 8;
    float4 v1 = *(const float4*)(X + (m0 + row) * 128 + c8);
    float4 v2 = *(const float4*)(X + (m0 + row) * 128 + c8 + 4);
    uint4 o = make_uint4(pk_bf16(v1.x, v1.y), pk_bf16(v1.z, v1.w),
                         pk_bf16(v2.x, v2.y), pk_bf16(v2.z, v2.w));
    *(uint4*)(&As[row * GXSTR + c8]) = o;
  }
  __syncthreads();

  const int w = tid >> 6, l = tid & 63, lr = l & 15, lg = l >> 4;

  v4f acc[8][2];
#pragma unroll
  for (int mt = 0; mt < 8; mt++) {
    acc[mt][0] = (v4f){0.f, 0.f, 0.f, 0.f};
    acc[mt][1] = (v4f){0.f, 0.f, 0.f, 0.f};
  }
  // phase 1: t1 = x @ W1
#pragma unroll
  for (int kt = 0; kt < 4; kt++) {
    short8 bfr[2];
#pragma unroll
    for (int ntl = 0; ntl < 2; ntl++)
      bfr[ntl] = *(const short8*)(Wp1 + (long)(kt * 8 + 2 * w + ntl) * 512 + l * 8);
#pragma unroll
    for (int mt = 0; mt < 8; mt++) {
      short8 af = *(const short8*)(&As[(mt * 16 + lr) * GXSTR + kt * 32 + lg * 8]);
      acc[mt][0] = __builtin_amdgcn_mfma_f32_16x16x32_bf16(af, bfr[0], acc[mt][0], 0, 0, 0);
      acc[mt][1] = __builtin_amdgcn_mfma_f32_16x16x32_bf16(af, bfr[1], acc[mt][1], 0, 0, 0);
    }
  }
  __syncthreads();   // all As (x) reads done

  // write t1 = relu(acc + b1) back into As
  {
    float bv[2] = {b1[a * 128 + 32 * w + lr], b1[a * 128 + 32 * w + 16 + lr]};
#pragma unroll
    for (int mt = 0; mt < 8; mt++)
#pragma unroll
      for (int ntl = 0; ntl < 2; ntl++)
#pragma unroll
        for (int i = 0; i < 4; i++) {
          int row = mt * 16 + lg * 4 + i;
          int col = 32 * w + ntl * 16 + lr;
          As[row * GXSTR + col] = f2bf(fmaxf(acc[mt][ntl][i] + bv[ntl], 0.0f));
        }
  }
  __syncthreads();

  // phase 2: h = t1 @ W2 + b2
#pragma unroll
  for (int mt = 0; mt < 8; mt++) {
    acc[mt][0] = (v4f){0.f, 0.f, 0.f, 0.f};
    acc[mt][1] = (v4f){0.f, 0.f, 0.f, 0.f};
  }
#pragma unroll
  for (int kt = 0; kt < 4; kt++) {
    short8 bfr[2];
#pragma unroll
    for (int ntl = 0; ntl < 2; ntl++)
      bfr[ntl] = *(const short8*)(Wp2 + (long)(kt * 8 + 2 * w + ntl) * 512 + l * 8);
#pragma unroll
    for (int mt = 0; mt < 8; mt++) {
      short8 af = *(const short8*)(&As[(mt * 16 + lr) * GXSTR + kt * 32 + lg * 8]);
      acc[mt][0] = __builtin_amdgcn_mfma_f32_16x16x32_bf16(af, bfr[0], acc[mt][0], 0, 0, 0);
      acc[mt][1] = __builtin_amdgcn_mfma_f32_16x16x32_bf16(af, bfr[1], acc[mt][1], 0, 0, 0);
    }
  }
  {
    float bv[2] = {b2[a * 128 + 32 * w + lr], b2[a * 128 + 32 * w + 16 + lr]};
#pragma unroll
    for (int mt = 0; mt < 8; mt++)
#pragma unroll
      for (int ntl = 0; ntl < 2; ntl++)
#pragma unroll
        for (int i = 0; i < 4; i++) {
          long row = m0 + mt * 16 + lg * 4 + i;
          int col = 32 * w + ntl * 16 + lr;
          H[row * 384 + a * 128 + col] = f2bf(acc[mt][ntl][i] + bv[ntl]);
        }
  }
}

// ---------------------------------------------------------------------------
// Standalone gather: agg[b,n,384] = sum_j h[b, csr[j], 384]. NO LDS.
// 16 lanes/node, depth-2 ping-pong, preloaded indices + ds_swizzle broadcast.
// launch_bounds(256,8): VGPR cap 64 (demand ~60) -> 8 waves/SIMD = 32/CU.
// Grid 2048 = one resident cohort on 256 CUs x 8 blocks.
// Same summation order + pk_bf16 rounding as the fused kernel -> identical.
// ---------------------------------------------------------------------------
__global__ __launch_bounds__(256, 8) void gather_k(
    const unsigned short* __restrict__ H, const int* __restrict__ offs,
    const int* __restrict__ csr, unsigned short* __restrict__ AGG) {
  const int tid = threadIdx.x;
  const long node0 = (long)blockIdx.x * 16;
  const int bt = (int)(node0 >> 14);
  const int nbase = (int)(node0 & (NN - 1));
  const int nd = tid >> 4;
  const int sub = tid & 15;
  const int n = nbase + nd;
  const int e0 = offs[n], e1 = offs[n + 1];
  const int cnt = e1 - e0;
  const unsigned short* hb = H + (long)bt * NN * 384 + sub * 24;
  f32x2 acc12[12];
#pragma unroll
  for (int i = 0; i < 12; i++) acc12[i] = (f32x2){0.f, 0.f};

  // cooperative index preload: covers 32 edges (99.99% of nodes)
  int i0, i1;
  { int a_ = e0 + sub;      a_ = (a_ < EE) ? a_ : (EE - 1); i0 = csr[a_]; }
  { int a_ = e0 + 16 + sub; a_ = (a_ < EE) ? a_ : (EE - 1); i1 = csr[a_]; }

#define ACC8(bp, u)                                                     \
    { acc12[bp+0] += (f32x2){bflo(u.x), bfhi(u.x)};                     \
      acc12[bp+1] += (f32x2){bflo(u.y), bfhi(u.y)};                     \
      acc12[bp+2] += (f32x2){bflo(u.z), bfhi(u.z)};                     \
      acc12[bp+3] += (f32x2){bflo(u.w), bfhi(u.w)}; }
#define GACC(BUF, KK)                                                   \
    if ((KK) < cnt) { ACC8(0, BUF##0) ACC8(4, BUF##1) ACC8(8, BUF##2) }
#define ROWLD(BUF, SPTR)                                                \
    { const unsigned short* p_ = hb + (long)(SPTR) * 384;               \
      BUF##0 = *(const uint4*)(p_);                                     \
      BUF##1 = *(const uint4*)(p_ + 8);                                 \
      BUF##2 = *(const uint4*)(p_ + 16); }
#define SWZ(reg, k) __builtin_amdgcn_ds_swizzle(reg, ((k) << 5) | 16)
#define IDXG(reg, k, e) (((e) < cnt) ? SWZ(reg, k) : 0)
  // depth-2: step k ACCs edge b+k (buf k&1), loads edge b+k+2 into same buf
#define BLOCK16_D2(b, ic, in)                                           \
    GACC(A, (b)+0)  ROWLD(A, IDXG(ic, 2,  (b)+2))                       \
    GACC(B, (b)+1)  ROWLD(B, IDXG(ic, 3,  (b)+3))                       \
    GACC(A, (b)+2)  ROWLD(A, IDXG(ic, 4,  (b)+4))                       \
    GACC(B, (b)+3)  ROWLD(B, IDXG(ic, 5,  (b)+5))                       \
    GACC(A, (b)+4)  ROWLD(A, IDXG(ic, 6,  (b)+6))                       \
    GACC(B, (b)+5)  ROWLD(B, IDXG(ic, 7,  (b)+7))                       \
    GACC(A, (b)+6)  ROWLD(A, IDXG(ic, 8,  (b)+8))                       \
    GACC(B, (b)+7)  ROWLD(B, IDXG(ic, 9,  (b)+9))                       \
    GACC(A, (b)+8)  ROWLD(A, IDXG(ic, 10, (b)+10))                      \
    GACC(B, (b)+9)  ROWLD(B, IDXG(ic, 11, (b)+11))                      \
    GACC(A, (b)+10) ROWLD(A, IDXG(ic, 12, (b)+12))                      \
    GACC(B, (b)+11) ROWLD(B, IDXG(ic, 13, (b)+13))                      \
    GACC(A, (b)+12) ROWLD(A, IDXG(ic, 14, (b)+14))                      \
    GACC(B, (b)+13) ROWLD(B, IDXG(ic, 15, (b)+15))                      \
    GACC(A, (b)+14) ROWLD(A, IDXG(in, 0,  (b)+16))                      \
    GACC(B, (b)+15) ROWLD(B, IDXG(in, 1,  (b)+17))

  uint4 A0, A1, A2, B0, B1, B2;
  {
    int t0 = IDXG(i0, 0, 0), t1 = IDXG(i0, 1, 1);
    ROWLD(A, t0) ROWLD(B, t1)
  }
  BLOCK16_D2(0, i0, i1)
  if (cnt > 16) {
    BLOCK16_D2(16, i1, i1)   // trailing prefetch (edges 32,33) is dead either
                             // way: guarded off if cnt<=32, re-done serially
                             // below if cnt>32 (never ACC'd from these bufs)
    if (cnt > 32) {          // P ~ 1e-4 per node: cold serial path
      for (int e = 32; e < cnt; e++) {
        int s0 = csr[e0 + e];
        const unsigned short* p0 = hb + (long)s0 * 384;
        uint4 F0 = *(const uint4*)(p0);
        uint4 F1 = *(const uint4*)(p0 + 8);
        uint4 F2 = *(const uint4*)(p0 + 16);
        ACC8(0, F0) ACC8(4, F1) ACC8(8, F2)
      }
    }
  }
#undef BLOCK16_D2
#undef IDXG
#undef SWZ
#undef ROWLD
#undef GACC
#undef ACC8

  // pack + store this thread's 48 contiguous bytes of agg
  uint4 o0 = make_uint4(pk_bf16(acc12[0].x, acc12[0].y),
                        pk_bf16(acc12[1].x, acc12[1].y),
                        pk_bf16(acc12[2].x, acc12[2].y),
                        pk_bf16(acc12[3].x, acc12[3].y));
  uint4 o1 = make_uint4(pk_bf16(acc12[4].x, acc12[4].y),
                        pk_bf16(acc12[5].x, acc12[5].y),
                        pk_bf16(acc12[6].x, acc12[6].y),
                        pk_bf16(acc12[7].x, acc12[7].y));
  uint4 o2 = make_uint4(pk_bf16(acc12[8].x, acc12[8].y),
                        pk_bf16(acc12[9].x, acc12[9].y),
                        pk_bf16(acc12[10].x, acc12[10].y),
                        pk_bf16(acc12[11].x, acc12[11].y));
  unsigned short* op = AGG + (node0 + (long)nd) * 384 + sub * 24;
  *(uint4*)(op) = o0;
  *(uint4*)(op + 8) = o1;
  *(uint4*)(op + 16) = o2;
}

// ---------------------------------------------------------------------------
// attn_post: attention + mu-MLP + noise/logp reading precomputed agg.
// Identical to attn_mega minus the gather (phase 0 = coalesced agg load).
// ---------------------------------------------------------------------------
#define XSTR 136
#define QSTR 34
__global__ __launch_bounds__(256, 3) void attn_post(
    const unsigned short* __restrict__ AGG,
    const unsigned short* __restrict__ WF,
    const float* __restrict__ bq, const float* __restrict__ bk,
    const float* __restrict__ bv, const float* __restrict__ bo,
    const unsigned short* __restrict__ WM1, const float* __restrict__ mb1,
    const unsigned short* __restrict__ WM2, const float* __restrict__ mb2,
    float* __restrict__ out0, float* __restrict__ out1) {
  __shared__ __align__(16) unsigned short xS[48 * XSTR];
  __shared__ __align__(16) unsigned short kS[4 * 48 * QSTR];
  __shared__ __align__(16) unsigned short vS[4 * 48 * QSTR];
  __shared__ float lpS[48];

  const int tid = threadIdx.x;
  const long node0 = (long)blockIdx.x * 16;

  // ---- phase 0: load agg -> xS rows (3*nd + a) ----
  {
    const int nd = tid >> 4;
    const int sub = tid & 15;
    const unsigned short* ag = AGG + (node0 + (long)nd) * 384 + sub * 24;
    uint4 r0 = *(const uint4*)(ag);
    uint4 r1 = *(const uint4*)(ag + 8);
    uint4 r2 = *(const uint4*)(ag + 16);
    unsigned pr[12] = {r0.x, r0.y, r0.z, r0.w,
                       r1.x, r1.y, r1.z, r1.w,
                       r2.x, r2.y, r2.z, r2.w};
#pragma unroll
    for (int jj = 0; jj < 12; jj++) {
      int g = sub * 24 + 2 * jj;
      int a_ = g >> 7;
      int c = g & 127;
      *(unsigned*)&xS[(3 * nd + a_) * XSTR + c] = pr[jj];
    }
  }
  __syncthreads();

  const int w = tid >> 6;
  const int l = tid & 63;
  const int lr = l & 15;
  const int lg = l >> 4;
  const unsigned short* WQ = WF;
  const unsigned short* WK = WF + 16384;
  const unsigned short* WV = WF + 32768;
  const unsigned short* WO = WF + 49152;

  // ---- phase 1: QKV projections ----
  v4f accq[3][2], acck[3][2], accv[3][2];
#pragma unroll
  for (int mt = 0; mt < 3; mt++)
#pragma unroll
    for (int n = 0; n < 2; n++) {
      accq[mt][n] = (v4f){0.f, 0.f, 0.f, 0.f};
      acck[mt][n] = (v4f){0.f, 0.f, 0.f, 0.f};
      accv[mt][n] = (v4f){0.f, 0.f, 0.f, 0.f};
    }
#pragma unroll
  for (int kt = 0; kt < 4; kt++) {
    short8 af[3];
#pragma unroll
    for (int mt = 0; mt < 3; mt++)
      af[mt] = *(const short8*)&xS[(mt * 16 + lr) * XSTR + kt * 32 + lg * 8];
#pragma unroll
    for (int ntl = 0; ntl < 2; ntl++) {
      long tf = (long)(kt * 8 + 2 * w + ntl) * 512 + l * 8;
      short8 b0 = *(const short8*)&WQ[tf];
      short8 b1 = *(const short8*)&WK[tf];
      short8 b2 = *(const short8*)&WV[tf];
#pragma unroll
      for (int mt = 0; mt < 3; mt++) {
        accq[mt][ntl] = __builtin_amdgcn_mfma_f32_16x16x32_bf16(af[mt], b0, accq[mt][ntl], 0, 0, 0);
        acck[mt][ntl] = __builtin_amdgcn_mfma_f32_16x16x32_bf16(af[mt], b1, acck[mt][ntl], 0, 0, 0);
        accv[mt][ntl] = __builtin_amdgcn_mfma_f32_16x16x32_bf16(af[mt], b2, accv[mt][ntl], 0, 0, 0);
      }
    }
  }
  __syncthreads();   // all waves' xS (agg) MFMA reads complete

  // residual pre-read (per-wave own head cols of xS), THEN write Q over them
  float resv[3][2][4];
#pragma unroll
  for (int mt = 0; mt < 3; mt++)
#pragma unroll
    for (int ntl = 0; ntl < 2; ntl++)
#pragma unroll
      for (int i = 0; i < 4; i++)
        resv[mt][ntl][i] =
            bf2f(xS[(mt * 16 + lg * 4 + i) * XSTR + 32 * w + ntl * 16 + lr]);

  {
    const float scale = 0.17677669529663687f;  // 1/sqrt(32)
    unsigned short* kw = &kS[w * 48 * QSTR];
    unsigned short* vw = &vS[w * 48 * QSTR];
    float bqv[2] = {bq[32 * w + lr], bq[32 * w + 16 + lr]};
    float bkv[2] = {bk[32 * w + lr], bk[32 * w + 16 + lr]};
    float bvv[2] = {bv[32 * w + lr], bv[32 * w + 16 + lr]};
#pragma unroll
    for (int mt = 0; mt < 3; mt++)
#pragma unroll
      for (int ntl = 0; ntl < 2; ntl++)
#pragma unroll
        for (int i = 0; i < 4; i++) {
          int row = mt * 16 + lg * 4 + i;
          int col = ntl * 16 + lr;
          xS[row * XSTR + 32 * w + col] = f2bf((accq[mt][ntl][i] + bqv[ntl]) * scale);
          kw[row * QSTR + col] = f2bf(acck[mt][ntl][i] + bkv[ntl]);
          vw[row * QSTR + col] = f2bf(accv[mt][ntl][i] + bvv[ntl]);
        }
  }
  __syncthreads();

  // ---- phase 2: attention; lane l<48 owns (nd=l/3, aq=l%3) of head w.
  if (l < 48) {
    int aq = l % 3;
    int ndr = l - aq;
    const unsigned* qr = (const unsigned*)&xS[l * XSTR + 32 * w];
    const unsigned* kr0 = (const unsigned*)&kS[(w * 48 + ndr) * QSTR];
    const unsigned* kr1 = (const unsigned*)&kS[(w * 48 + ndr + 1) * QSTR];
    const unsigned* kr2 = (const unsigned*)&kS[(w * 48 + ndr + 2) * QSTR];
    float s0 = 0.f, s1 = 0.f, s2 = 0.f;
#pragma unroll
    for (int j = 0; j < 16; j++) {
      unsigned uq = qr[j], u0 = kr0[j], u1 = kr1[j], u2 = kr2[j];
      float qa = bflo(uq), qb = bfhi(uq);
      s0 = fmaf(qa, bflo(u0), fmaf(qb, bfhi(u0), s0));
      s1 = fmaf(qa, bflo(u1), fmaf(qb, bfhi(u1), s1));
      s2 = fmaf(qa, bflo(u2), fmaf(qb, bfhi(u2), s2));
    }
    float mx = fmaxf(s0, fmaxf(s1, s2));
    float e0 = expf(s0 - mx), e1 = expf(s1 - mx), e2 = expf(s2 - mx);
    float inv = 1.0f / (e0 + e1 + e2);
    e0 *= inv; e1 *= inv; e2 *= inv;
    const unsigned* vr0 = (const unsigned*)&vS[(w * 48 + ndr) * QSTR];
    const unsigned* vr1 = (const unsigned*)&vS[(w * 48 + ndr + 1) * QSTR];
    const unsigned* vr2 = (const unsigned*)&vS[(w * 48 + ndr + 2) * QSTR];
    unsigned ov[16];
#pragma unroll
    for (int j = 0; j < 16; j++) {
      unsigned u0 = vr0[j], u1 = vr1[j], u2 = vr2[j];
      float oa = fmaf(e0, bflo(u0), fmaf(e1, bflo(u1), e2 * bflo(u2)));
      float ob = fmaf(e0, bfhi(u0), fmaf(e1, bfhi(u1), e2 * bfhi(u2)));
      ov[j] = pk_bf16(oa, ob);
    }
    uint4* orow = (uint4*)&xS[l * XSTR + 32 * w];
    orow[0] = make_uint4(ov[0], ov[1], ov[2], ov[3]);
    orow[1] = make_uint4(ov[4], ov[5], ov[6], ov[7]);
    orow[2] = make_uint4(ov[8], ov[9], ov[10], ov[11]);
    orow[3] = make_uint4(ov[12], ov[13], ov[14], ov[15]);
  }
  __syncthreads();

  // ---- phase 3: hI = agg + O @ Wo + bo ----
  v4f acco[3][2];
#pragma unroll
  for (int mt = 0; mt < 3; mt++)
#pragma unroll
    for (int n = 0; n < 2; n++) acco[mt][n] = (v4f){0.f, 0.f, 0.f, 0.f};
#pragma unroll
  for (int kt = 0; kt < 4; kt++) {
    short8 af[3];
#pragma unroll
    for (int mt = 0; mt < 3; mt++)
      af[mt] = *(const short8*)&xS[(mt * 16 + lr) * XSTR + kt * 32 + lg * 8];
#pragma unroll
    for (int ntl = 0; ntl < 2; ntl++) {
      long tf = (long)(kt * 8 + 2 * w + ntl) * 512 + l * 8;
      short8 b = *(const short8*)&WO[tf];
#pragma unroll
      for (int mt = 0; mt < 3; mt++)
        acco[mt][ntl] = __builtin_amdgcn_mfma_f32_16x16x32_bf16(af[mt], b, acco[mt][ntl], 0, 0, 0);
    }
  }
  __syncthreads();   // all O reads of xS done

  // write hI into xS, a-major rows: row' = a*16 + nd  (orig row = 3*nd + a)
  {
    float bov[2] = {bo[32 * w + lr], bo[32 * w + 16 + lr]};
#pragma unroll
    for (int mt = 0; mt < 3; mt++)
#pragma unroll
      for (int ntl = 0; ntl < 2; ntl++)
#pragma unroll
        for (int i = 0; i < 4; i++) {
          int row = mt * 16 + lg * 4 + i;
          int nd = row / 3, a_ = row - nd * 3;
          int gcol = 32 * w + ntl * 16 + lr;
          xS[(a_ * 16 + nd) * XSTR + gcol] =
              f2bf(acco[mt][ntl][i] + bov[ntl] + resv[mt][ntl][i]);
        }
  }
  __syncthreads();

  // ---- phase 4: m = relu(hI @ mu_W1[a] + mb1[a]); tile mt == a ----
  v4f accm[3][2];
#pragma unroll
  for (int mt = 0; mt < 3; mt++)
#pragma unroll
    for (int n = 0; n < 2; n++) accm[mt][n] = (v4f){0.f, 0.f, 0.f, 0.f};
#pragma unroll
  for (int kt = 0; kt < 4; kt++) {
#pragma unroll
    for (int mt = 0; mt < 3; mt++) {
      short8 af = *(const short8*)&xS[(mt * 16 + lr) * XSTR + kt * 32 + lg * 8];
#pragma unroll
      for (int ntl = 0; ntl < 2; ntl++) {
        short8 b = *(const short8*)(WM1 + (long)mt * 16384 +
                                    (long)(kt * 8 + 2 * w + ntl) * 512 + l * 8);
        accm[mt][ntl] = __builtin_amdgcn_mfma_f32_16x16x32_bf16(af, b, accm[mt][ntl], 0, 0, 0);
      }
    }
  }
  __syncthreads();   // all hI reads done

  // write m into xS (already a-major: tile mt rows = a*16 + nd)
#pragma unroll
  for (int mt = 0; mt < 3; mt++)
#pragma unroll
    for (int ntl = 0; ntl < 2; ntl++) {
      int col = 32 * w + ntl * 16 + lr;
      float bias = mb1[mt * 128 + col];
#pragma unroll
      for (int i = 0; i < 4; i++) {
        int rowp = mt * 16 + lg * 4 + i;
        xS[rowp * XSTR + col] = f2bf(fmaxf(accm[mt][ntl][i] + bias, 0.0f));
      }
    }
  __syncthreads();

  // ---- phase 5: mu = m @ mu_W2[a] + mb2[a]; wave w handles a = w (w<3) ----
  if (w < 3) {
    v4f accu = (v4f){0.f, 0.f, 0.f, 0.f};
#pragma unroll
    for (int kt = 0; kt < 4; kt++) {
      short8 af = *(const short8*)&xS[(w * 16 + lr) * XSTR + kt * 32 + lg * 8];
      short8 b = *(const short8*)(WM2 + w * 2048 + kt * 512 + l * 8);
      accu = __builtin_amdgcn_mfma_f32_16x16x32_bf16(af, b, accu, 0, 0, 0);
    }
    float bias = mb2[w * 16 + lr];
#pragma unroll
    for (int i = 0; i < 4; i++) {
      int nd = lg * 4 + i;
      float mu = accu[i] + bias;
      unsigned gidx = (unsigned)((node0 + nd) * 48 + w * 16 + lr);
      unsigned bits = jax_random_bits32(gidx);
      float noise = jax_normal_from_bits(bits);
      float sample = mu + noise;
      float lp = -0.9189385332046727f - 0.5f * noise * noise;
      lp += __shfl_xor(lp, 1, 64);
      lp += __shfl_xor(lp, 2, 64);
      lp += __shfl_xor(lp, 4, 64);
      lp += __shfl_xor(lp, 8, 64);
      if (lr == 0) lpS[w * 16 + nd] = lp;
      float res;
      if (w == 0) {
        float th = tanhf(sample);
        float mx = th;
        mx = fmaxf(mx, __shfl_xor(mx, 1, 64));
        mx = fmaxf(mx, __shfl_xor(mx, 2, 64));
        mx = fmaxf(mx, __shfl_xor(mx, 4, 64));
        mx = fmaxf(mx, __shfl_xor(mx, 8, 64));
        float ex = expf(th - mx);
        float ss = ex;
        ss += __shfl_xor(ss, 1, 64);
        ss += __shfl_xor(ss, 2, 64);
        ss += __shfl_xor(ss, 4, 64);
        ss += __shfl_xor(ss, 8, 64);
        res = ex / ss;
      } else if (w == 1) {
        res = 1.0f / (1.0f + expf(-sample));
      } else {
        res = tanhf(sample);
      }
      out0[gidx] = res;
    }
  }
  __syncthreads();
  if (tid < 16)
    out1[node0 + tid] = lpS[tid] + lpS[16 + tid] + lpS[32 + tid];
}

// ---------------------------------------------------------------------------
// Fallback fused kernel (R6-verified, 90.5us) — used if workspace too small
// for the split path's agg buffer.
// ---------------------------------------------------------------------------
__global__ __launch_bounds__(256, 3) void attn_mega(
    const unsigned short* __restrict__ H, const int* __restrict__ offs,
    const int* __restrict__ csr,
    const unsigned short* __restrict__ WF,
    const float* __restrict__ bq, const float* __restrict__ bk,
    const float* __restrict__ bv, const float* __restrict__ bo,
    const unsigned short* __restrict__ WM1, const float* __restrict__ mb1,
    const unsigned short* __restrict__ WM2, const float* __restrict__ mb2,
    float* __restrict__ out0, float* __restrict__ out1) {
  __shared__ __align__(16) unsigned short xS[48 * XSTR];
  __shared__ __align__(16) unsigned short kS[4 * 48 * QSTR];
  __shared__ __align__(16) unsigned short vS[4 * 48 * QSTR];
  __shared__ float lpS[48];

  const int tid = threadIdx.x;
  const long node0 = (long)blockIdx.x * 16;

  {
    const int bt = (int)(node0 >> 14);
    const int nbase = (int)(node0 & (NN - 1));
    const int nd = tid >> 4;
    const int sub = tid & 15;
    const int n = nbase + nd;
    const int e0 = offs[n], e1 = offs[n + 1];
    const int cnt = e1 - e0;
    const unsigned short* hb = H + (long)bt * NN * 384 + sub * 24;
    f32x2 acc12[12];
#pragma unroll
    for (int i = 0; i < 12; i++) acc12[i] = (f32x2){0.f, 0.f};

    int i0, i1, i2, i3;
    { int a_ = e0 + sub;      a_ = (a_ < EE) ? a_ : (EE - 1); i0 = csr[a_]; }
    { int a_ = e0 + 16 + sub; a_ = (a_ < EE) ? a_ : (EE - 1); i1 = csr[a_]; }
    { int a_ = e0 + 32 + sub; a_ = (a_ < EE) ? a_ : (EE - 1); i2 = csr[a_]; }
    { int a_ = e0 + 48 + sub; a_ = (a_ < EE) ? a_ : (EE - 1); i3 = csr[a_]; }

#define ACC8(bp, u)                                                     \
    { acc12[bp+0] += (f32x2){bflo(u.x), bfhi(u.x)};                     \
      acc12[bp+1] += (f32x2){bflo(u.y), bfhi(u.y)};                     \
      acc12[bp+2] += (f32x2){bflo(u.z), bfhi(u.z)};                     \
      acc12[bp+3] += (f32x2){bflo(u.w), bfhi(u.w)}; }
#define GACC(BUF, KK)                                                   \
    if ((KK) < cnt) { ACC8(0, BUF##0) ACC8(4, BUF##1) ACC8(8, BUF##2) }
#define ROWLD(BUF, SPTR)                                                \
    { const unsigned short* p_ = hb + (long)(SPTR) * 384;               \
      BUF##0 = *(const uint4*)(p_);                                     \
      BUF##1 = *(const uint4*)(p_ + 8);                                 \
      BUF##2 = *(const uint4*)(p_ + 16); }
#define SWZ(reg, k) __builtin_amdgcn_ds_swizzle(reg, ((k) << 5) | 16)
#define IDXG(reg, k, e) (((e) < cnt) ? SWZ(reg, k) : 0)
#define BLOCK16(b, ic, in)                                              \
    GACC(A, (b)+0)  ROWLD(A, IDXG(ic, 4,  (b)+4))                       \
    GACC(B, (b)+1)  ROWLD(B, IDXG(ic, 5,  (b)+5))                       \
    GACC(C, (b)+2)  ROWLD(C, IDXG(ic, 6,  (b)+6))                       \
    GACC(D, (b)+3)  ROWLD(D, IDXG(ic, 7,  (b)+7))                       \
    GACC(A, (b)+4)  ROWLD(A, IDXG(ic, 8,  (b)+8))                       \
    GACC(B, (b)+5)  ROWLD(B, IDXG(ic, 9,  (b)+9))                       \
    GACC(C, (b)+6)  ROWLD(C, IDXG(ic, 10, (b)+10))                      \
    GACC(D, (b)+7)  ROWLD(D, IDXG(ic, 11, (b)+11))                      \
    GACC(A, (b)+8)  ROWLD(A, IDXG(ic, 12, (b)+12))                      \
    GACC(B, (b)+9)  ROWLD(B, IDXG(ic, 13, (b)+13))                      \
    GACC(C, (b)+10) ROWLD(C, IDXG(ic, 14, (b)+14))                      \
    GACC(D, (b)+11) ROWLD(D, IDXG(ic, 15, (b)+15))                      \
    GACC(A, (b)+12) ROWLD(A, IDXG(in, 0,  (b)+16))                      \
    GACC(B, (b)+13) ROWLD(B, IDXG(in, 1,  (b)+17))                      \
    GACC(C, (b)+14) ROWLD(C, IDXG(in, 2,  (b)+18))                      \
    GACC(D, (b)+15) ROWLD(D, IDXG(in, 3,  (b)+19))

    uint4 A0, A1, A2, B0, B1, B2, C0, C1, C2, D0, D1, D2;
    {
      int t0 = IDXG(i0, 0, 0), t1 = IDXG(i0, 1, 1);
      int t2 = IDXG(i0, 2, 2), t3 = IDXG(i0, 3, 3);
      ROWLD(A, t0) ROWLD(B, t1) ROWLD(C, t2) ROWLD(D, t3)
    }
    BLOCK16(0, i0, i1)
    if (cnt > 16) {
      BLOCK16(16, i1, i2)
      if (cnt > 32) {
        BLOCK16(32, i2, i3)
        if (cnt > 48) {
          BLOCK16(48, i3, i3)
        }
      }
    }
    if (cnt > 64) {
      for (int e = 64; e < cnt; e++) {
        int s0 = csr[e0 + e];
        const unsigned short* p0 = hb + (long)s0 * 384;
        uint4 F0 = *(const uint4*)(p0);
        uint4 F1 = *(const uint4*)(p0 + 8);
        uint4 F2 = *(const uint4*)(p0 + 16);
        ACC8(0, F0) ACC8(4, F1) ACC8(8, F2)
      }
    }
#undef BLOCK16
#undef IDXG
#undef SWZ
#undef ROWLD
#undef GACC
#undef ACC8
#pragma unroll
    for (int jj = 0; jj < 12; jj++) {
      int g = sub * 24 + 2 * jj;
      int a_ = g >> 7;
      int c = g & 127;
      *(unsigned*)&xS[(3 * nd + a_) * XSTR + c] =
          pk_bf16(acc12[jj].x, acc12[jj].y);
    }
  }
  __syncthreads();

  const int w = tid >> 6;
  const int l = tid & 63;
  const int lr = l & 15;
  const int lg = l >> 4;
  const unsigned short* WQ = WF;
  const unsigned short* WK = WF + 16384;
  const unsigned short* WV = WF + 32768;
  const unsigned short* WO = WF + 49152;

  v4f accq[3][2], acck[3][2], accv[3][2];
#pragma unroll
  for (int mt = 0; mt < 3; mt++)
#pragma unroll
    for (int n = 0; n < 2; n++) {
      accq[mt][n] = (v4f){0.f, 0.f, 0.f, 0.f};
      acck[mt][n] = (v4f){0.f, 0.f, 0.f, 0.f};
      accv[mt][n] = (v4f){0.f, 0.f, 0.f, 0.f};
    }
#pragma unroll
  for (int kt = 0; kt < 4; kt++) {
    short8 af[3];
#pragma unroll
    for (int mt = 0; mt < 3; mt++)
      af[mt] = *(const short8*)&xS[(mt * 16 + lr) * XSTR + kt * 32 + lg * 8];
#pragma unroll
    for (int ntl = 0; ntl < 2; ntl++) {
      long tf = (long)(kt * 8 + 2 * w + ntl) * 512 + l * 8;
      short8 b0 = *(const short8*)&WQ[tf];
      short8 b1 = *(const short8*)&WK[tf];
      short8 b2 = *(const short8*)&WV[tf];
#pragma unroll
      for (int mt = 0; mt < 3; mt++) {
        accq[mt][ntl] = __builtin_amdgcn_mfma_f32_16x16x32_bf16(af[mt], b0, accq[mt][ntl], 0, 0, 0);
        acck[mt][ntl] = __builtin_amdgcn_mfma_f32_16x16x32_bf16(af[mt], b1, acck[mt][ntl], 0, 0, 0);
        accv[mt][ntl] = __builtin_amdgcn_mfma_f32_16x16x32_bf16(af[mt], b2, accv[mt][ntl], 0, 0, 0);
      }
    }
  }
  __syncthreads();

  float resv[3][2][4];
#pragma unroll
  for (int mt = 0; mt < 3; mt++)
#pragma unroll
    for (int ntl = 0; ntl < 2; ntl++)
#pragma unroll
      for (int i = 0; i < 4; i++)
        resv[mt][ntl][i] =
            bf2f(xS[(mt * 16 + lg * 4 + i) * XSTR + 32 * w + ntl * 16 + lr]);

  {
    const float scale = 0.17677669529663687f;
    unsigned short* kw = &kS[w * 48 * QSTR];
    unsigned short* vw = &vS[w * 48 * QSTR];
    float bqv[2] = {bq[32 * w + lr], bq[32 * w + 16 + lr]};
    float bkv[2] = {bk[32 * w + lr], bk[32 * w + 16 + lr]};
    float bvv[2] = {bv[32 * w + lr], bv[32 * w + 16 + lr]};
#pragma unroll
    for (int mt = 0; mt < 3; mt++)
#pragma unroll
      for (int ntl = 0; ntl < 2; ntl++)
#pragma unroll
        for (int i = 0; i < 4; i++) {
          int row = mt * 16 + lg * 4 + i;
          int col = ntl * 16 + lr;
          xS[row * XSTR + 32 * w + col] = f2bf((accq[mt][ntl][i] + bqv[ntl]) * scale);
          kw[row * QSTR + col] = f2bf(acck[mt][ntl][i] + bkv[ntl]);
          vw[row * QSTR + col] = f2bf(accv[mt][ntl][i] + bvv[ntl]);
        }
  }
  __syncthreads();

  if (l < 48) {
    int aq = l % 3;
    int ndr = l - aq;
    const unsigned* qr = (const unsigned*)&xS[l * XSTR + 32 * w];
    const unsigned* kr0 = (const unsigned*)&kS[(w * 48 + ndr) * QSTR];
    const unsigned* kr1 = (const unsigned*)&kS[(w * 48 + ndr + 1) * QSTR];
    const unsigned* kr2 = (const unsigned*)&kS[(w * 48 + ndr + 2) * QSTR];
    float s0 = 0.f, s1 = 0.f, s2 = 0.f;
#pragma unroll
    for (int j = 0; j < 16; j++) {
      unsigned uq = qr[j], u0 = kr0[j], u1 = kr1[j], u2 = kr2[j];
      float qa = bflo(uq), qb = bfhi(uq);
      s0 = fmaf(qa, bflo(u0), fmaf(qb, bfhi(u0), s0));
      s1 = fmaf(qa, bflo(u1), fmaf(qb, bfhi(u1), s1));
      s2 = fmaf(qa, bflo(u2), fmaf(qb, bfhi(u2), s2));
    }
    float mx = fmaxf(s0, fmaxf(s1, s2));
    float e0 = expf(s0 - mx), e1 = expf(s1 - mx), e2 = expf(s2 - mx);
    float inv = 1.0f / (e0 + e1 + e2);
    e0 *= inv; e1 *= inv; e2 *= inv;
    const unsigned* vr0 = (const unsigned*)&vS[(w * 48 + ndr) * QSTR];
    const unsigned* vr1 = (const unsigned*)&vS[(w * 48 + ndr + 1) * QSTR];
    const unsigned* vr2 = (const unsigned*)&vS[(w * 48 + ndr + 2) * QSTR];
    unsigned ov[16];
#pragma unroll
    for (int j = 0; j < 16; j++) {
      unsigned u0 = vr0[j], u1 = vr1[j], u2 = vr2[j];
      float oa = fmaf(e0, bflo(u0), fmaf(e1, bflo(u1), e2 * bflo(u2)));
      float ob = fmaf(e0, bfhi(u0), fmaf(e1, bfhi(u1), e2 * bfhi(u2)));
      ov[j] = pk_bf16(oa, ob);
    }
    uint4* orow = (uint4*)&xS[l * XSTR + 32 * w];
    orow[0] = make_uint4(ov[0], ov[1], ov[2], ov[3]);
    orow[1] = make_uint4(ov[4], ov[5], ov[6], ov[7]);
    orow[2] = make_uint4(ov[8], ov[9], ov[10], ov[11]);
    orow[3] = make_uint4(ov[12], ov[13], ov[14], ov[15]);
  }
  __syncthreads();

  v4f acco[3][2];
#pragma unroll
  for (int mt = 0; mt < 3; mt++)
#pragma unroll
    for (int n = 0; n < 2; n++) acco[mt][n] = (v4f){0.f, 0.f, 0.f, 0.f};
#pragma unroll
  for (int kt = 0; kt < 4; kt++) {
    short8 af[3];
#pragma unroll
    for (int mt = 0; mt < 3; mt++)
      af[mt] = *(const short8*)&xS[(mt * 16 + lr) * XSTR + kt * 32 + lg * 8];
#pragma unroll
    for (int ntl = 0; ntl < 2; ntl++) {
      long tf = (long)(kt * 8 + 2 * w + ntl) * 512 + l * 8;
      short8 b = *(const short8*)&WO[tf];
#pragma unroll
      for (int mt = 0; mt < 3; mt++)
        acco[mt][ntl] = __builtin_amdgcn_mfma_f32_16x16x32_bf16(af[mt], b, acco[mt][ntl], 0, 0, 0);
    }
  }
  __syncthreads();

  {
    float bov[2] = {bo[32 * w + lr], bo[32 * w + 16 + lr]};
#pragma unroll
    for (int mt = 0; mt < 3; mt++)
#pragma unroll
      for (int ntl = 0; ntl < 2; ntl++)
#pragma unroll
        for (int i = 0; i < 4; i++) {
          int row = mt * 16 + lg * 4 + i;
          int nd = row / 3, a_ = row - nd * 3;
          int gcol = 32 * w + ntl * 16 + lr;
          xS[(a_ * 16 + nd) * XSTR + gcol] =
              f2bf(acco[mt][ntl][i] + bov[ntl] + resv[mt][ntl][i]);
        }
  }
  __syncthreads();

  v4f accm[3][2];
#pragma unroll
  for (int mt = 0; mt < 3; mt++)
#pragma unroll
    for (int n = 0; n < 2; n++) accm[mt][n] = (v4f){0.f, 0.f, 0.f, 0.f};
#pragma unroll
  for (int kt = 0; kt < 4; kt++) {
#pragma unroll
    for (int mt = 0; mt < 3; mt++) {
      short8 af = *(const short8*)&xS[(mt * 16 + lr) * XSTR + kt * 32 + lg * 8];
#pragma unroll
      for (int ntl = 0; ntl < 2; ntl++) {
        short8 b = *(const short8*)(WM1 + (long)mt * 16384 +
                                    (long)(kt * 8 + 2 * w + ntl) * 512 + l * 8);
        accm[mt][ntl] = __builtin_amdgcn_mfma_f32_16x16x32_bf16(af, b, accm[mt][ntl], 0, 0, 0);
      }
    }
  }
  __syncthreads();

#pragma unroll
  for (int mt = 0; mt < 3; mt++)
#pragma unroll
    for (int ntl = 0; ntl < 2; ntl++) {
      int col = 32 * w + ntl * 16 + lr;
      float bias = mb1[mt * 128 + col];
#pragma unroll
      for (int i = 0; i < 4; i++) {
        int rowp = mt * 16 + lg * 4 + i;
        xS[rowp * XSTR + col] = f2bf(fmaxf(accm[mt][ntl][i] + bias, 0.0f));
      }
    }
  __syncthreads();

  if (w < 3) {
    v4f accu = (v4f){0.f, 0.f, 0.f, 0.f};
#pragma unroll
    for (int kt = 0; kt < 4; kt++) {
      short8 af = *(const short8*)&xS[(w * 16 + lr) * XSTR + kt * 32 + lg * 8];
      short8 b = *(const short8*)(WM2 + w * 2048 + kt * 512 + l * 8);
      accu = __builtin_amdgcn_mfma_f32_16x16x32_bf16(af, b, accu, 0, 0, 0);
    }
    float bias = mb2[w * 16 + lr];
#pragma unroll
    for (int i = 0; i < 4; i++) {
      int nd = lg * 4 + i;
      float mu = accu[i] + bias;
      unsigned gidx = (unsigned)((node0 + nd) * 48 + w * 16 + lr);
      unsigned bits = jax_random_bits32(gidx);
      float noise = jax_normal_from_bits(bits);
      float sample = mu + noise;
      float lp = -0.9189385332046727f - 0.5f * noise * noise;
      lp += __shfl_xor(lp, 1, 64);
      lp += __shfl_xor(lp, 2, 64);
      lp += __shfl_xor(lp, 4, 64);
      lp += __shfl_xor(lp, 8, 64);
      if (lr == 0) lpS[w * 16 + nd] = lp;
      float res;
      if (w == 0) {
        float th = tanhf(sample);
        float mx = th;
        mx = fmaxf(mx, __shfl_xor(mx, 1, 64));
        mx = fmaxf(mx, __shfl_xor(mx, 2, 64));
        mx = fmaxf(mx, __shfl_xor(mx, 4, 64));
        mx = fmaxf(mx, __shfl_xor(mx, 8, 64));
        float ex = expf(th - mx);
        float ss = ex;
        ss += __shfl_xor(ss, 1, 64);
        ss += __shfl_xor(ss, 2, 64);
        ss += __shfl_xor(ss, 4, 64);
        ss += __shfl_xor(ss, 8, 64);
        res = ex / ss;
      } else if (w == 1) {
        res = 1.0f / (1.0f + expf(-sample));
      } else {
        res = tanhf(sample);
      }
      out0[gidx] = res;
    }
  }
  __syncthreads();
  if (tid < 16)
    out1[node0 + tid] = lpS[tid] + lpS[16 + tid] + lpS[32 + tid];
}

// ---------------------------------------------------------------------------
extern "C" void kernel_launch(void* const* d_in, const int* in_sizes, int n_in,
                              void* d_out, int out_size, void* d_ws, size_t ws_size,
                              hipStream_t stream) {
  const float* x = (const float*)d_in[0];
  const int* ei = (const int*)d_in[1];
  const float* W1 = (const float*)d_in[2];
  const float* b1 = (const float*)d_in[3];
  const float* W2 = (const float*)d_in[4];
  const float* b2 = (const float*)d_in[5];
  const float* Wq = (const float*)d_in[6];
  const float* bq = (const float*)d_in[7];
  const float* Wk = (const float*)d_in[8];
  const float* bk = (const float*)d_in[9];
  const float* Wv = (const float*)d_in[10];
  const float* bv = (const float*)d_in[11];
  const float* Wo = (const float*)d_in[12];
  const float* bo = (const float*)d_in[13];
  const float* mW1 = (const float*)d_in[14];
  const float* mb1 = (const float*)d_in[15];
  const float* mW2 = (const float*)d_in[16];
  const float* mb2 = (const float*)d_in[17];
  (void)in_sizes; (void)n_in; (void)out_size;

  unsigned short* HB = (unsigned short*)d_ws;      // 12,582,912 (h bf16)
  int* deg = (int*)(HB + 12582912);                // 16384
  int* offs = deg + NN;                            // 16385
  int* cur = offs + (NN + 1);                      // 16384
  int* csr = cur + NN;                             // 262144
  unsigned short* wfrag = (unsigned short*)(((uintptr_t)(csr + EE) + 15) & ~(uintptr_t)15);
  unsigned short* w2frag = wfrag + 13 * 16384;     // 3*2048
  unsigned short* aggB = (unsigned short*)(((uintptr_t)(w2frag + 6144) + 15) & ~(uintptr_t)15);
  size_t needed = (size_t)((char*)(aggB + 12582912) - (char*)d_ws);

  const int* dst = ei;
  const int* srcv = ei + EE;

  float* out0 = (float*)d_out;
  float* out1 = out0 + TOT_NOISE;

  hipMemsetAsync(deg, 0, NN * sizeof(int), stream);
  edge_count<<<EE / 256, 256, 0, stream>>>(dst, deg);
  scan_k<<<1, 1024, 0, stream>>>(deg, offs, cur);
  edge_fill<<<EE / 256, 256, 0, stream>>>(dst, srcv, cur, csr);
  prep_wfrag<<<dim3(64, 14), 256, 0, stream>>>(W1, W2, mW1, Wq, Wk, Wv, Wo, mW2, wfrag);

  // h = relu(x@W1+b1)@W2 + b2  (fused 2-layer MLP)
  mlp_fused<<<dim3(BNODES / 128, 3), 256, 0, stream>>>(x, wfrag, b1, wfrag + 3 * 16384, b2, HB);

  if (ws_size >= needed) {
    // split path: high-occupancy gather, then attention pipeline
    gather_k<<<BNODES / 16, 256, 0, stream>>>(HB, offs, csr, aggB);
    attn_post<<<BNODES / 16, 256, 0, stream>>>(aggB,
                                               wfrag + 9 * 16384, bq, bk, bv, bo,
                                               wfrag + 6 * 16384, mb1, w2frag, mb2,
                                               out0, out1);
  } else {
    // fallback: fused (R6-verified)
    attn_mega<<<BNODES / 16, 256, 0, stream>>>(HB, offs, csr,
                                               wfrag + 9 * 16384, bq, bk, bv, bo,
                                               wfrag + 6 * 16384, mb1, w2frag, mb2,
                                               out0, out1);
  }
}

// Round 8
// 234.238 us; speedup vs baseline: 1.0224x; 1.0224x over previous
//
#include <hip/hip_runtime.h>
#include <hip/hip_bf16.h>

// Problem constants
#define NN    16384      // N nodes
#define EE    262144     // edges
#define BNODES 32768     // B*N
#define AH    384        // A*H
#define TOT_NOISE 1572864u

typedef __attribute__((ext_vector_type(8))) short short8;
typedef __attribute__((ext_vector_type(4))) float v4f;
typedef __attribute__((ext_vector_type(2))) float f32x2;

__device__ __forceinline__ unsigned short f2bf(float f) {
  unsigned u = __float_as_uint(f);
  unsigned r = u + 0x7fffu + ((u >> 16) & 1u);
  return (unsigned short)(r >> 16);
}
__device__ __forceinline__ float bf2f(unsigned short h) {
  return __uint_as_float(((unsigned)h) << 16);
}
__device__ __forceinline__ float bflo(unsigned u) { return __uint_as_float(u << 16); }
__device__ __forceinline__ float bfhi(unsigned u) { return __uint_as_float(u & 0xffff0000u); }
// HW packed fp32x2 -> bf16x2 (v_cvt_pk_bf16_f32, RNE — identical to f2bf)
__device__ __forceinline__ unsigned pk_bf16(float a, float b) {
  __hip_bfloat162 h = __float22bfloat162_rn(make_float2(a, b));
  return *(unsigned*)&h;
}

// ---------------------------------------------------------------------------
// Threefry-2x32, keys = (0, 42)
// ---------------------------------------------------------------------------
__device__ __forceinline__ void threefry2x32_042(unsigned& x0, unsigned& x1) {
  const unsigned ks0 = 0u;
  const unsigned ks1 = 42u;
  const unsigned ks2 = 0x1BD11BDAu ^ 0u ^ 42u;
  x0 += ks0; x1 += ks1;
#define TFR(r) { x0 += x1; x1 = (x1 << (r)) | (x1 >> (32 - (r))); x1 ^= x0; }
  TFR(13) TFR(15) TFR(26) TFR(6)   x0 += ks1; x1 += ks2 + 1u;
  TFR(17) TFR(29) TFR(16) TFR(24)  x0 += ks2; x1 += ks0 + 2u;
  TFR(13) TFR(15) TFR(26) TFR(6)   x0 += ks0; x1 += ks1 + 3u;
  TFR(17) TFR(29) TFR(16) TFR(24)  x0 += ks1; x1 += ks2 + 4u;
  TFR(13) TFR(15) TFR(26) TFR(6)   x0 += ks2; x1 += ks0 + 5u;
#undef TFR
}

// XLA ErfInv32 (Giles) polynomial
__device__ __forceinline__ float erfinv_f32(float x) {
  float w = -log1pf(-x * x);
  float p;
  if (w < 5.0f) {
    w -= 2.5f;
    p = 2.81022636e-08f;
    p = fmaf(p, w, 3.43273939e-07f);
    p = fmaf(p, w, -3.5233877e-06f);
    p = fmaf(p, w, -4.39150654e-06f);
    p = fmaf(p, w, 0.00021858087f);
    p = fmaf(p, w, -0.00125372503f);
    p = fmaf(p, w, -0.00417768164f);
    p = fmaf(p, w, 0.246640727f);
    p = fmaf(p, w, 1.50140941f);
  } else {
    w = sqrtf(w) - 3.0f;
    p = -0.000200214257f;
    p = fmaf(p, w, 0.000100950558f);
    p = fmaf(p, w, 0.00134934322f);
    p = fmaf(p, w, -0.00367342844f);
    p = fmaf(p, w, 0.00573950773f);
    p = fmaf(p, w, -0.0076224613f);
    p = fmaf(p, w, 0.00943887047f);
    p = fmaf(p, w, 1.00167406f);
    p = fmaf(p, w, 2.83297682f);
  }
  return p * x;
}

__device__ __forceinline__ unsigned jax_random_bits32(unsigned i) {
  unsigned x0 = 0u, x1 = i;
  threefry2x32_042(x0, x1);
  return x0 ^ x1;
}

__device__ __forceinline__ float jax_normal_from_bits(unsigned bits) {
  float f = __uint_as_float((bits >> 9) | 0x3f800000u) - 1.0f;  // [0,1)
  const float lo = -0.99999994f;                                 // nextafter(-1,0)
  float u = f * 2.0f + lo;
  u = fmaxf(u, lo);
  return 1.4142135623730951f * erfinv_f32(u);
}

// ---------------------------------------------------------------------------
// CSR build
// ---------------------------------------------------------------------------
__global__ void edge_count(const int* __restrict__ dst, int* __restrict__ deg) {
  int e = blockIdx.x * 256 + threadIdx.x;
  if (e < EE) atomicAdd(&deg[dst[e]], 1);
}

__global__ __launch_bounds__(1024) void scan_k(const int* __restrict__ deg,
                                               int* __restrict__ offs,
                                               int* __restrict__ cur) {
  __shared__ int wsum[16];
  const int t = threadIdx.x;
  const int base = t * 16;
  int loc[16];
  int s = 0;
#pragma unroll
  for (int i = 0; i < 16; i++) { loc[i] = deg[base + i]; s += loc[i]; }
  const int mysum = s;
  const int lane = t & 63, wid = t >> 6;
#pragma unroll
  for (int off = 1; off < 64; off <<= 1) {
    int v = __shfl_up(s, off, 64);
    if (lane >= off) s += v;
  }
  if (lane == 63) wsum[wid] = s;
  __syncthreads();
  if (t == 0) {
    int r = 0;
#pragma unroll
    for (int i = 0; i < 16; i++) { int v = wsum[i]; wsum[i] = r; r += v; }
  }
  __syncthreads();
  int run = wsum[wid] + s - mysum;
#pragma unroll
  for (int i = 0; i < 16; i++) {
    offs[base + i] = run;
    cur[base + i] = run;
    run += loc[i];
  }
  if (t == 1023) offs[NN] = run;
}

__global__ void edge_fill(const int* __restrict__ dst, const int* __restrict__ srcv,
                          int* __restrict__ cur, int* __restrict__ csr) {
  int e = blockIdx.x * 256 + threadIdx.x;
  if (e < EE) {
    int d = dst[e];
    int p = atomicAdd(&cur[d], 1);
    csr[p] = srcv[e];
  }
}

// ---------------------------------------------------------------------------
// Weight prep: slots 0-2: W1[a]; 3-5: W2[a]; 6-8: mu_W1[a]; 9:Wq 10:Wk 11:Wv
// 12:Wo  (each 16384)  |  slot 13 region: mu_W2 fragments (3 x 2048)
// ---------------------------------------------------------------------------
__global__ __launch_bounds__(256) void prep_wfrag(
    const float* __restrict__ W1, const float* __restrict__ W2,
    const float* __restrict__ mW1,
    const float* __restrict__ Wq, const float* __restrict__ Wk,
    const float* __restrict__ Wv, const float* __restrict__ Wo,
    const float* __restrict__ mW2,
    unsigned short* __restrict__ F) {
  int m = blockIdx.y;
  int f = blockIdx.x * 256 + threadIdx.x;
  if (m == 13) {   // mu_W2: A x 128 x 16
    if (f < 6144) {
      int a = f >> 11;
      int r2 = f & 2047;
      int kt = r2 >> 9;
      int r = r2 & 511;
      int lane = r >> 3, j = r & 7;
      int k = kt * 32 + (lane >> 4) * 8 + j;
      int n = lane & 15;
      F[13 * 16384 + f] = f2bf(mW2[(a * 128 + k) * 16 + n]);
    }
    return;
  }
  const float* W;
  if (m < 3) W = W1 + (long)m * 16384;
  else if (m < 6) W = W2 + (long)(m - 3) * 16384;
  else if (m < 9) W = mW1 + (long)(m - 6) * 16384;
  else W = (m == 9) ? Wq : (m == 10) ? Wk : (m == 11) ? Wv : Wo;
  int tile = f >> 9;
  int kt = tile >> 3, nt = tile & 7;
  int r = f & 511;
  int lane = r >> 3, j = r & 7;
  int k = kt * 32 + (lane >> 4) * 8 + j;
  int n = nt * 16 + (lane & 15);
  F[(long)m * 16384 + f] = f2bf(W[k * 128 + n]);
}

// ---------------------------------------------------------------------------
// Fused 2-layer MLP: h = relu(x@W1+b1)@W2 + b2, per a. 128-row tiles.
// R8: swapped-operand MFMA (acc = C^T: lane holds node row mt*16+lr,
// 4 consecutive feature cols) -> paired u32 epilogue stores.
// ---------------------------------------------------------------------------
#define GXSTR 136
__global__ __launch_bounds__(256, 4) void mlp_fused(
    const float* __restrict__ X,
    const unsigned short* __restrict__ WF1, const float* __restrict__ b1,
    const unsigned short* __restrict__ WF2, const float* __restrict__ b2,
    unsigned short* __restrict__ H) {
  __shared__ __align__(16) unsigned short As[128 * GXSTR];
  const int a = blockIdx.y;
  const long m0 = (long)blockIdx.x * 128;
  const int tid = threadIdx.x;
  const unsigned short* Wp1 = WF1 + (long)a * 16384;
  const unsigned short* Wp2 = WF2 + (long)a * 16384;

  // stage x tile fp32 -> bf16 (HW packed convert)
#pragma unroll
  for (int p = 0; p < 8; p++) {
    int c = tid + p * 256;
    int row = c >> 4, c8 = (c & 15) * 8;
    float4 v1 = *(const float4*)(X + (m0 + row) * 128 + c8);
    float4 v2 = *(const float4*)(X + (m0 + row) * 128 + c8 + 4);
    uint4 o = make_uint4(pk_bf16(v1.x, v1.y), pk_bf16(v1.z, v1.w),
                         pk_bf16(v2.x, v2.y), pk_bf16(v2.z, v2.w));
    *(uint4*)(&As[row * GXSTR + c8]) = o;
  }
  __syncthreads();

  const int w = tid >> 6, l = tid & 63, lr = l & 15, lg = l >> 4;

  v4f acc[8][2];
#pragma unroll
  for (int mt = 0; mt < 8; mt++) {
    acc[mt][0] = (v4f){0.f, 0.f, 0.f, 0.f};
    acc[mt][1] = (v4f){0.f, 0.f, 0.f, 0.f};
  }
  // phase 1: t1 = x @ W1  (swapped: acc = (x@W1)^T fragment layout)
#pragma unroll
  for (int kt = 0; kt < 4; kt++) {
    short8 bfr[2];
#pragma unroll
    for (int ntl = 0; ntl < 2; ntl++)
      bfr[ntl] = *(const short8*)(Wp1 + (long)(kt * 8 + 2 * w + ntl) * 512 + l * 8);
#pragma unroll
    for (int mt = 0; mt < 8; mt++) {
      short8 af = *(const short8*)(&As[(mt * 16 + lr) * GXSTR + kt * 32 + lg * 8]);
      acc[mt][0] = __builtin_amdgcn_mfma_f32_16x16x32_bf16(bfr[0], af, acc[mt][0], 0, 0, 0);
      acc[mt][1] = __builtin_amdgcn_mfma_f32_16x16x32_bf16(bfr[1], af, acc[mt][1], 0, 0, 0);
    }
  }
  __syncthreads();   // all As (x) reads done

  // write t1 = relu(acc + b1) back into As (paired u32 stores)
  {
#pragma unroll
    for (int mt = 0; mt < 8; mt++) {
      const int nrow = mt * 16 + lr;
#pragma unroll
      for (int ntl = 0; ntl < 2; ntl++) {
        const int c0 = 32 * w + ntl * 16 + lg * 4;
        float4 b4 = *(const float4*)&b1[a * 128 + c0];
        unsigned* dq = (unsigned*)&As[nrow * GXSTR + c0];
        dq[0] = pk_bf16(fmaxf(acc[mt][ntl][0] + b4.x, 0.0f),
                        fmaxf(acc[mt][ntl][1] + b4.y, 0.0f));
        dq[1] = pk_bf16(fmaxf(acc[mt][ntl][2] + b4.z, 0.0f),
                        fmaxf(acc[mt][ntl][3] + b4.w, 0.0f));
      }
    }
  }
  __syncthreads();

  // phase 2: h = t1 @ W2 + b2
#pragma unroll
  for (int mt = 0; mt < 8; mt++) {
    acc[mt][0] = (v4f){0.f, 0.f, 0.f, 0.f};
    acc[mt][1] = (v4f){0.f, 0.f, 0.f, 0.f};
  }
#pragma unroll
  for (int kt = 0; kt < 4; kt++) {
    short8 bfr[2];
#pragma unroll
    for (int ntl = 0; ntl < 2; ntl++)
      bfr[ntl] = *(const short8*)(Wp2 + (long)(kt * 8 + 2 * w + ntl) * 512 + l * 8);
#pragma unroll
    for (int mt = 0; mt < 8; mt++) {
      short8 af = *(const short8*)(&As[(mt * 16 + lr) * GXSTR + kt * 32 + lg * 8]);
      acc[mt][0] = __builtin_amdgcn_mfma_f32_16x16x32_bf16(bfr[0], af, acc[mt][0], 0, 0, 0);
      acc[mt][1] = __builtin_amdgcn_mfma_f32_16x16x32_bf16(bfr[1], af, acc[mt][1], 0, 0, 0);
    }
  }
  {
#pragma unroll
    for (int mt = 0; mt < 8; mt++) {
      const long row = m0 + mt * 16 + lr;
#pragma unroll
      for (int ntl = 0; ntl < 2; ntl++) {
        const int c0 = 32 * w + ntl * 16 + lg * 4;
        float4 b4 = *(const float4*)&b2[a * 128 + c0];
        unsigned* dq = (unsigned*)&H[row * 384 + a * 128 + c0];
        dq[0] = pk_bf16(acc[mt][ntl][0] + b4.x, acc[mt][ntl][1] + b4.y);
        dq[1] = pk_bf16(acc[mt][ntl][2] + b4.z, acc[mt][ntl][3] + b4.w);
      }
    }
  }
}

// ---------------------------------------------------------------------------
// Mega-fused: gather + attention + mu-MLP + noise/logp. 16 nodes/block.
// Gather: R6-verified (depth-4 rolling buffers, preloaded indices, ds_swizzle
// broadcast, packed f32x2 acc). MFMA phases 1/3/4 use swapped operands
// (C^T layout: lane holds one node row x 4 consecutive feature cols) ->
// epilogues use paired pk_bf16 + u32 stores (half the LDS stores/converts).
// Phase 2 (attention) and phase 5 (mu+noise) keep their original layouts.
// launch_bounds(256,3): only verified spill-free config (R2/R4/R5).
// ---------------------------------------------------------------------------
#define XSTR 136
#define QSTR 34
__global__ __launch_bounds__(256, 3) void attn_mega(
    const unsigned short* __restrict__ H, const int* __restrict__ offs,
    const int* __restrict__ csr,
    const unsigned short* __restrict__ WF,
    const float* __restrict__ bq, const float* __restrict__ bk,
    const float* __restrict__ bv, const float* __restrict__ bo,
    const unsigned short* __restrict__ WM1, const float* __restrict__ mb1,
    const unsigned short* __restrict__ WM2, const float* __restrict__ mb2,
    float* __restrict__ out0, float* __restrict__ out1) {
  __shared__ __align__(16) unsigned short xS[48 * XSTR];
  __shared__ __align__(16) unsigned short kS[4 * 48 * QSTR];
  __shared__ __align__(16) unsigned short vS[4 * 48 * QSTR];
  __shared__ float lpS[48];

  const int tid = threadIdx.x;
  const long node0 = (long)blockIdx.x * 16;

  // ---- phase 0: gather + segment-sum agg for 16 nodes directly into xS ----
  {
    const int bt = (int)(node0 >> 14);           // batch
    const int nbase = (int)(node0 & (NN - 1));
    const int nd = tid >> 4;                     // 0..15 local node
    const int sub = tid & 15;                    // 0..15 col group (24 bf16)
    const int n = nbase + nd;
    const int e0 = offs[n], e1 = offs[n + 1];
    const int cnt = e1 - e0;
    const unsigned short* hb = H + (long)bt * NN * 384 + sub * 24;
    f32x2 acc12[12];
#pragma unroll
    for (int i = 0; i < 12; i++) acc12[i] = (f32x2){0.f, 0.f};

    // preload ALL indices (4 chunks of 16 edges); latency paid once, together
    int i0, i1, i2, i3;
    { int a_ = e0 + sub;      a_ = (a_ < EE) ? a_ : (EE - 1); i0 = csr[a_]; }
    { int a_ = e0 + 16 + sub; a_ = (a_ < EE) ? a_ : (EE - 1); i1 = csr[a_]; }
    { int a_ = e0 + 32 + sub; a_ = (a_ < EE) ? a_ : (EE - 1); i2 = csr[a_]; }
    { int a_ = e0 + 48 + sub; a_ = (a_ < EE) ? a_ : (EE - 1); i3 = csr[a_]; }

    // packed accumulate: 2 unpacks + 1 v_pk_add_f32 per bf16 pair
#define ACC8(bp, u)                                                     \
    { acc12[bp+0] += (f32x2){bflo(u.x), bfhi(u.x)};                     \
      acc12[bp+1] += (f32x2){bflo(u.y), bfhi(u.y)};                     \
      acc12[bp+2] += (f32x2){bflo(u.z), bfhi(u.z)};                     \
      acc12[bp+3] += (f32x2){bflo(u.w), bfhi(u.w)}; }
#define GACC(BUF, KK)                                                   \
    if ((KK) < cnt) { ACC8(0, BUF##0) ACC8(4, BUF##1) ACC8(8, BUF##2) }
#define ROWLD(BUF, SPTR)                                                \
    { const unsigned short* p_ = hb + (long)(SPTR) * 384;               \
      BUF##0 = *(const uint4*)(p_);                                     \
      BUF##1 = *(const uint4*)(p_ + 8);                                 \
      BUF##2 = *(const uint4*)(p_ + 16); }
    // ds_swizzle BitMode (k<<5)|16: new_lane = (lane & 16) | k within each
    // 32-half -> broadcast slot k to its 16-lane group (HW-verified R3).
#define SWZ(reg, k) __builtin_amdgcn_ds_swizzle(reg, ((k) << 5) | 16)
#define IDXG(reg, k, e) (((e) < cnt) ? SWZ(reg, k) : 0)
#define BLOCK16(b, ic, in)                                              \
    GACC(A, (b)+0)  ROWLD(A, IDXG(ic, 4,  (b)+4))                       \
    GACC(B, (b)+1)  ROWLD(B, IDXG(ic, 5,  (b)+5))                       \
    GACC(C, (b)+2)  ROWLD(C, IDXG(ic, 6,  (b)+6))                       \
    GACC(D, (b)+3)  ROWLD(D, IDXG(ic, 7,  (b)+7))                       \
    GACC(A, (b)+4)  ROWLD(A, IDXG(ic, 8,  (b)+8))                       \
    GACC(B, (b)+5)  ROWLD(B, IDXG(ic, 9,  (b)+9))                       \
    GACC(C, (b)+6)  ROWLD(C, IDXG(ic, 10, (b)+10))                      \
    GACC(D, (b)+7)  ROWLD(D, IDXG(ic, 11, (b)+11))                      \
    GACC(A, (b)+8)  ROWLD(A, IDXG(ic, 12, (b)+12))                      \
    GACC(B, (b)+9)  ROWLD(B, IDXG(ic, 13, (b)+13))                      \
    GACC(C, (b)+10) ROWLD(C, IDXG(ic, 14, (b)+14))                      \
    GACC(D, (b)+11) ROWLD(D, IDXG(ic, 15, (b)+15))                      \
    GACC(A, (b)+12) ROWLD(A, IDXG(in, 0,  (b)+16))                      \
    GACC(B, (b)+13) ROWLD(B, IDXG(in, 1,  (b)+17))                      \
    GACC(C, (b)+14) ROWLD(C, IDXG(in, 2,  (b)+18))                      \
    GACC(D, (b)+15) ROWLD(D, IDXG(in, 3,  (b)+19))

    uint4 A0, A1, A2, B0, B1, B2, C0, C1, C2, D0, D1, D2;
    {
      int t0 = IDXG(i0, 0, 0), t1 = IDXG(i0, 1, 1);
      int t2 = IDXG(i0, 2, 2), t3 = IDXG(i0, 3, 3);
      ROWLD(A, t0) ROWLD(B, t1) ROWLD(C, t2) ROWLD(D, t3)
    }
    BLOCK16(0, i0, i1)
    if (cnt > 16) {
      BLOCK16(16, i1, i2)
      if (cnt > 32) {
        BLOCK16(32, i2, i3)
        if (cnt > 48) {
          BLOCK16(48, i3, i3)
        }
      }
    }
    if (cnt > 64) {
      for (int e = 64; e < cnt; e++) {
        int s0 = csr[e0 + e];
        const unsigned short* p0 = hb + (long)s0 * 384;
        uint4 F0 = *(const uint4*)(p0);
        uint4 F1 = *(const uint4*)(p0 + 8);
        uint4 F2 = *(const uint4*)(p0 + 16);
        ACC8(0, F0) ACC8(4, F1) ACC8(8, F2)
      }
    }
#undef BLOCK16
#undef IDXG
#undef SWZ
#undef ROWLD
#undef GACC
#undef ACC8
    // write agg -> xS rows (3*nd + a), packed pairs (pairs never cross a)
#pragma unroll
    for (int jj = 0; jj < 12; jj++) {
      int g = sub * 24 + 2 * jj;
      int a_ = g >> 7;
      int c = g & 127;
      *(unsigned*)&xS[(3 * nd + a_) * XSTR + c] =
          pk_bf16(acc12[jj].x, acc12[jj].y);
    }
  }
  __syncthreads();

  const int w = tid >> 6;
  const int l = tid & 63;
  const int lr = l & 15;
  const int lg = l >> 4;
  const unsigned short* WQ = WF;
  const unsigned short* WK = WF + 16384;
  const unsigned short* WV = WF + 32768;
  const unsigned short* WO = WF + 49152;

  // ---- phase 1: QKV projections (swapped operands: acc = C^T layout) ----
  v4f accq[3][2], acck[3][2], accv[3][2];
#pragma unroll
  for (int mt = 0; mt < 3; mt++)
#pragma unroll
    for (int n = 0; n < 2; n++) {
      accq[mt][n] = (v4f){0.f, 0.f, 0.f, 0.f};
      acck[mt][n] = (v4f){0.f, 0.f, 0.f, 0.f};
      accv[mt][n] = (v4f){0.f, 0.f, 0.f, 0.f};
    }
#pragma unroll
  for (int kt = 0; kt < 4; kt++) {
    short8 af[3];
#pragma unroll
    for (int mt = 0; mt < 3; mt++)
      af[mt] = *(const short8*)&xS[(mt * 16 + lr) * XSTR + kt * 32 + lg * 8];
#pragma unroll
    for (int ntl = 0; ntl < 2; ntl++) {
      long tf = (long)(kt * 8 + 2 * w + ntl) * 512 + l * 8;
      short8 b0 = *(const short8*)&WQ[tf];
      short8 b1 = *(const short8*)&WK[tf];
      short8 b2 = *(const short8*)&WV[tf];
#pragma unroll
      for (int mt = 0; mt < 3; mt++) {
        accq[mt][ntl] = __builtin_amdgcn_mfma_f32_16x16x32_bf16(b0, af[mt], accq[mt][ntl], 0, 0, 0);
        acck[mt][ntl] = __builtin_amdgcn_mfma_f32_16x16x32_bf16(b1, af[mt], acck[mt][ntl], 0, 0, 0);
        accv[mt][ntl] = __builtin_amdgcn_mfma_f32_16x16x32_bf16(b2, af[mt], accv[mt][ntl], 0, 0, 0);
      }
    }
  }
  __syncthreads();   // all waves' xS (agg) MFMA reads complete

  // residual pre-read (lane's own Q-write footprint: row mt*16+lr,
  // cols c0..c0+3), THEN write Q over it — paired u32 accesses
  float resv[3][2][4];
#pragma unroll
  for (int mt = 0; mt < 3; mt++)
#pragma unroll
    for (int ntl = 0; ntl < 2; ntl++) {
      const unsigned* xr =
          (const unsigned*)&xS[(mt * 16 + lr) * XSTR + 32 * w + ntl * 16 + lg * 4];
      unsigned u0 = xr[0], u1 = xr[1];
      resv[mt][ntl][0] = bflo(u0); resv[mt][ntl][1] = bfhi(u0);
      resv[mt][ntl][2] = bflo(u1); resv[mt][ntl][3] = bfhi(u1);
    }

  {
    const float scale = 0.17677669529663687f;  // 1/sqrt(32)
    unsigned short* kw = &kS[w * 48 * QSTR];
    unsigned short* vw = &vS[w * 48 * QSTR];
#pragma unroll
    for (int mt = 0; mt < 3; mt++) {
      const int nrow = mt * 16 + lr;
#pragma unroll
      for (int ntl = 0; ntl < 2; ntl++) {
        const int c0 = 32 * w + ntl * 16 + lg * 4;   // xS feature col
        const int ch = ntl * 16 + lg * 4;            // head-local col
        float4 bq4 = *(const float4*)&bq[c0];
        float4 bk4 = *(const float4*)&bk[c0];
        float4 bv4 = *(const float4*)&bv[c0];
        unsigned* xq = (unsigned*)&xS[nrow * XSTR + c0];
        xq[0] = pk_bf16((accq[mt][ntl][0] + bq4.x) * scale,
                        (accq[mt][ntl][1] + bq4.y) * scale);
        xq[1] = pk_bf16((accq[mt][ntl][2] + bq4.z) * scale,
                        (accq[mt][ntl][3] + bq4.w) * scale);
        unsigned* kq = (unsigned*)&kw[nrow * QSTR + ch];
        kq[0] = pk_bf16(acck[mt][ntl][0] + bk4.x, acck[mt][ntl][1] + bk4.y);
        kq[1] = pk_bf16(acck[mt][ntl][2] + bk4.z, acck[mt][ntl][3] + bk4.w);
        unsigned* vq = (unsigned*)&vw[nrow * QSTR + ch];
        vq[0] = pk_bf16(accv[mt][ntl][0] + bv4.x, accv[mt][ntl][1] + bv4.y);
        vq[1] = pk_bf16(accv[mt][ntl][2] + bv4.z, accv[mt][ntl][3] + bv4.w);
      }
    }
  }
  __syncthreads();

  // ---- phase 2: attention; lane l<48 owns (nd=l/3, aq=l%3) of head w.
  // O overwrites lane's own Q row in xS — race-free. (unchanged layout)
  if (l < 48) {
    int aq = l % 3;
    int ndr = l - aq;
    const unsigned* qr = (const unsigned*)&xS[l * XSTR + 32 * w];
    const unsigned* kr0 = (const unsigned*)&kS[(w * 48 + ndr) * QSTR];
    const unsigned* kr1 = (const unsigned*)&kS[(w * 48 + ndr + 1) * QSTR];
    const unsigned* kr2 = (const unsigned*)&kS[(w * 48 + ndr + 2) * QSTR];
    float s0 = 0.f, s1 = 0.f, s2 = 0.f;
#pragma unroll
    for (int j = 0; j < 16; j++) {
      unsigned uq = qr[j], u0 = kr0[j], u1 = kr1[j], u2 = kr2[j];
      float qa = bflo(uq), qb = bfhi(uq);
      s0 = fmaf(qa, bflo(u0), fmaf(qb, bfhi(u0), s0));
      s1 = fmaf(qa, bflo(u1), fmaf(qb, bfhi(u1), s1));
      s2 = fmaf(qa, bflo(u2), fmaf(qb, bfhi(u2), s2));
    }
    float mx = fmaxf(s0, fmaxf(s1, s2));
    float e0 = expf(s0 - mx), e1 = expf(s1 - mx), e2 = expf(s2 - mx);
    float inv = 1.0f / (e0 + e1 + e2);
    e0 *= inv; e1 *= inv; e2 *= inv;
    const unsigned* vr0 = (const unsigned*)&vS[(w * 48 + ndr) * QSTR];
    const unsigned* vr1 = (const unsigned*)&vS[(w * 48 + ndr + 1) * QSTR];
    const unsigned* vr2 = (const unsigned*)&vS[(w * 48 + ndr + 2) * QSTR];
    unsigned ov[16];
#pragma unroll
    for (int j = 0; j < 16; j++) {
      unsigned u0 = vr0[j], u1 = vr1[j], u2 = vr2[j];
      float oa = fmaf(e0, bflo(u0), fmaf(e1, bflo(u1), e2 * bflo(u2)));
      float ob = fmaf(e0, bfhi(u0), fmaf(e1, bfhi(u1), e2 * bfhi(u2)));
      ov[j] = pk_bf16(oa, ob);
    }
    uint4* orow = (uint4*)&xS[l * XSTR + 32 * w];
    orow[0] = make_uint4(ov[0], ov[1], ov[2], ov[3]);
    orow[1] = make_uint4(ov[4], ov[5], ov[6], ov[7]);
    orow[2] = make_uint4(ov[8], ov[9], ov[10], ov[11]);
    orow[3] = make_uint4(ov[12], ov[13], ov[14], ov[15]);
  }
  __syncthreads();

  // ---- phase 3: hI = agg + O @ Wo + bo (swapped operands) ----
  v4f acco[3][2];
#pragma unroll
  for (int mt = 0; mt < 3; mt++)
#pragma unroll
    for (int n = 0; n < 2; n++) acco[mt][n] = (v4f){0.f, 0.f, 0.f, 0.f};
#pragma unroll
  for (int kt = 0; kt < 4; kt++) {
    short8 af[3];
#pragma unroll
    for (int mt = 0; mt < 3; mt++)
      af[mt] = *(const short8*)&xS[(mt * 16 + lr) * XSTR + kt * 32 + lg * 8];
#pragma unroll
    for (int ntl = 0; ntl < 2; ntl++) {
      long tf = (long)(kt * 8 + 2 * w + ntl) * 512 + l * 8;
      short8 b = *(const short8*)&WO[tf];
#pragma unroll
      for (int mt = 0; mt < 3; mt++)
        acco[mt][ntl] = __builtin_amdgcn_mfma_f32_16x16x32_bf16(b, af[mt], acco[mt][ntl], 0, 0, 0);
    }
  }
  __syncthreads();   // all O reads of xS done

  // write hI into xS, a-major rows: node row nrow=3*nd+a_ -> row' = a_*16+nd
  {
#pragma unroll
    for (int mt = 0; mt < 3; mt++) {
      const int nrow = mt * 16 + lr;
      const int nd = nrow / 3;
      const int a_ = nrow - nd * 3;
      const int drow = a_ * 16 + nd;
#pragma unroll
      for (int ntl = 0; ntl < 2; ntl++) {
        const int c0 = 32 * w + ntl * 16 + lg * 4;
        float4 bo4 = *(const float4*)&bo[c0];
        unsigned* dq = (unsigned*)&xS[drow * XSTR + c0];
        dq[0] = pk_bf16(acco[mt][ntl][0] + bo4.x + resv[mt][ntl][0],
                        acco[mt][ntl][1] + bo4.y + resv[mt][ntl][1]);
        dq[1] = pk_bf16(acco[mt][ntl][2] + bo4.z + resv[mt][ntl][2],
                        acco[mt][ntl][3] + bo4.w + resv[mt][ntl][3]);
      }
    }
  }
  __syncthreads();

  // ---- phase 4: m = relu(hI @ mu_W1[a] + mb1[a]); tile mt == a (swapped) ----
  v4f accm[3][2];
#pragma unroll
  for (int mt = 0; mt < 3; mt++)
#pragma unroll
    for (int n = 0; n < 2; n++) accm[mt][n] = (v4f){0.f, 0.f, 0.f, 0.f};
#pragma unroll
  for (int kt = 0; kt < 4; kt++) {
#pragma unroll
    for (int mt = 0; mt < 3; mt++) {
      short8 af = *(const short8*)&xS[(mt * 16 + lr) * XSTR + kt * 32 + lg * 8];
#pragma unroll
      for (int ntl = 0; ntl < 2; ntl++) {
        short8 b = *(const short8*)(WM1 + (long)mt * 16384 +
                                    (long)(kt * 8 + 2 * w + ntl) * 512 + l * 8);
        accm[mt][ntl] = __builtin_amdgcn_mfma_f32_16x16x32_bf16(b, af, accm[mt][ntl], 0, 0, 0);
      }
    }
  }
  __syncthreads();   // all hI reads done

  // write m into xS (a-major: row = mt*16 + lr), paired u32 stores
  {
#pragma unroll
    for (int mt = 0; mt < 3; mt++) {
      const int nrow = mt * 16 + lr;
#pragma unroll
      for (int ntl = 0; ntl < 2; ntl++) {
        const int c0 = 32 * w + ntl * 16 + lg * 4;
        float4 b4 = *(const float4*)&mb1[mt * 128 + c0];
        unsigned* dq = (unsigned*)&xS[nrow * XSTR + c0];
        dq[0] = pk_bf16(fmaxf(accm[mt][ntl][0] + b4.x, 0.0f),
                        fmaxf(accm[mt][ntl][1] + b4.y, 0.0f));
        dq[1] = pk_bf16(fmaxf(accm[mt][ntl][2] + b4.z, 0.0f),
                        fmaxf(accm[mt][ntl][3] + b4.w, 0.0f));
      }
    }
  }
  __syncthreads();

  // ---- phase 5: mu = m @ mu_W2[a] + mb2[a]; wave w handles a = w (w<3).
  // UNSWAPPED (output layout feeds the lr-lane softmax/noise directly).
  if (w < 3) {
    v4f accu = (v4f){0.f, 0.f, 0.f, 0.f};
#pragma unroll
    for (int kt = 0; kt < 4; kt++) {
      short8 af = *(const short8*)&xS[(w * 16 + lr) * XSTR + kt * 32 + lg * 8];
      short8 b = *(const short8*)(WM2 + w * 2048 + kt * 512 + l * 8);
      accu = __builtin_amdgcn_mfma_f32_16x16x32_bf16(af, b, accu, 0, 0, 0);
    }
    float bias = mb2[w * 16 + lr];
#pragma unroll
    for (int i = 0; i < 4; i++) {
      int nd = lg * 4 + i;
      float mu = accu[i] + bias;
      unsigned gidx = (unsigned)((node0 + nd) * 48 + w * 16 + lr);
      unsigned bits = jax_random_bits32(gidx);
      float noise = jax_normal_from_bits(bits);
      float sample = mu + noise;
      float lp = -0.9189385332046727f - 0.5f * noise * noise;
      lp += __shfl_xor(lp, 1, 64);
      lp += __shfl_xor(lp, 2, 64);
      lp += __shfl_xor(lp, 4, 64);
      lp += __shfl_xor(lp, 8, 64);
      if (lr == 0) lpS[w * 16 + nd] = lp;
      float res;
      if (w == 0) {
        float th = tanhf(sample);
        float mx = th;
        mx = fmaxf(mx, __shfl_xor(mx, 1, 64));
        mx = fmaxf(mx, __shfl_xor(mx, 2, 64));
        mx = fmaxf(mx, __shfl_xor(mx, 4, 64));
        mx = fmaxf(mx, __shfl_xor(mx, 8, 64));
        float ex = expf(th - mx);
        float ss = ex;
        ss += __shfl_xor(ss, 1, 64);
        ss += __shfl_xor(ss, 2, 64);
        ss += __shfl_xor(ss, 4, 64);
        ss += __shfl_xor(ss, 8, 64);
        res = ex / ss;
      } else if (w == 1) {
        res = 1.0f / (1.0f + expf(-sample));
      } else {
        res = tanhf(sample);
      }
      out0[gidx] = res;
    }
  }
  __syncthreads();
  if (tid < 16)
    out1[node0 + tid] = lpS[tid] + lpS[16 + tid] + lpS[32 + tid];
}

// ---------------------------------------------------------------------------
extern "C" void kernel_launch(void* const* d_in, const int* in_sizes, int n_in,
                              void* d_out, int out_size, void* d_ws, size_t ws_size,
                              hipStream_t stream) {
  const float* x = (const float*)d_in[0];
  const int* ei = (const int*)d_in[1];
  const float* W1 = (const float*)d_in[2];
  const float* b1 = (const float*)d_in[3];
  const float* W2 = (const float*)d_in[4];
  const float* b2 = (const float*)d_in[5];
  const float* Wq = (const float*)d_in[6];
  const float* bq = (const float*)d_in[7];
  const float* Wk = (const float*)d_in[8];
  const float* bk = (const float*)d_in[9];
  const float* Wv = (const float*)d_in[10];
  const float* bv = (const float*)d_in[11];
  const float* Wo = (const float*)d_in[12];
  const float* bo = (const float*)d_in[13];
  const float* mW1 = (const float*)d_in[14];
  const float* mb1 = (const float*)d_in[15];
  const float* mW2 = (const float*)d_in[16];
  const float* mb2 = (const float*)d_in[17];
  (void)in_sizes; (void)n_in; (void)out_size; (void)ws_size;

  unsigned short* HB = (unsigned short*)d_ws;      // 12,582,912 (h bf16)
  int* deg = (int*)(HB + 12582912);                // 16384
  int* offs = deg + NN;                            // 16385
  int* cur = offs + (NN + 1);                      // 16384
  int* csr = cur + NN;                             // 262144
  unsigned short* wfrag = (unsigned short*)(((uintptr_t)(csr + EE) + 15) & ~(uintptr_t)15);
  unsigned short* w2frag = wfrag + 13 * 16384;     // 3*2048

  const int* dst = ei;
  const int* srcv = ei + EE;

  float* out0 = (float*)d_out;
  float* out1 = out0 + TOT_NOISE;

  hipMemsetAsync(deg, 0, NN * sizeof(int), stream);
  edge_count<<<EE / 256, 256, 0, stream>>>(dst, deg);
  scan_k<<<1, 1024, 0, stream>>>(deg, offs, cur);
  edge_fill<<<EE / 256, 256, 0, stream>>>(dst, srcv, cur, csr);
  prep_wfrag<<<dim3(64, 14), 256, 0, stream>>>(W1, W2, mW1, Wq, Wk, Wv, Wo, mW2, wfrag);

  // h = relu(x@W1+b1)@W2 + b2  (fused 2-layer MLP)
  mlp_fused<<<dim3(BNODES / 128, 3), 256, 0, stream>>>(x, wfrag, b1, wfrag + 3 * 16384, b2, HB);
  // gather + attention + hI + mu-MLP + noise/logp (mega-fused)
  attn_mega<<<BNODES / 16, 256, 0, stream>>>(HB, offs, csr,
                                             wfrag + 9 * 16384, bq, bk, bv, bo,
                                             wfrag + 6 * 16384, mb1, w2frag, mb2,
                                             out0, out1);
}

// Round 9
// 224.928 us; speedup vs baseline: 1.0648x; 1.0414x over previous
//
#include <hip/hip_runtime.h>
#include <hip/hip_bf16.h>

// Problem constants
#define NN    16384      // N nodes
#define EE    262144     // edges
#define BNODES 32768     // B*N
#define AH    384        // A*H
#define TOT_NOISE 1572864u

typedef __attribute__((ext_vector_type(8))) short short8;
typedef __attribute__((ext_vector_type(4))) float v4f;
typedef __attribute__((ext_vector_type(2))) float f32x2;

__device__ __forceinline__ unsigned short f2bf(float f) {
  unsigned u = __float_as_uint(f);
  unsigned r = u + 0x7fffu + ((u >> 16) & 1u);
  return (unsigned short)(r >> 16);
}
__device__ __forceinline__ float bf2f(unsigned short h) {
  return __uint_as_float(((unsigned)h) << 16);
}
__device__ __forceinline__ float bflo(unsigned u) { return __uint_as_float(u << 16); }
__device__ __forceinline__ float bfhi(unsigned u) { return __uint_as_float(u & 0xffff0000u); }
// HW packed fp32x2 -> bf16x2 (v_cvt_pk_bf16_f32, RNE — identical to f2bf)
__device__ __forceinline__ unsigned pk_bf16(float a, float b) {
  __hip_bfloat162 h = __float22bfloat162_rn(make_float2(a, b));
  return *(unsigned*)&h;
}

// ---------------------------------------------------------------------------
// Threefry-2x32, keys = (0, 42)
// ---------------------------------------------------------------------------
__device__ __forceinline__ void threefry2x32_042(unsigned& x0, unsigned& x1) {
  const unsigned ks0 = 0u;
  const unsigned ks1 = 42u;
  const unsigned ks2 = 0x1BD11BDAu ^ 0u ^ 42u;
  x0 += ks0; x1 += ks1;
#define TFR(r) { x0 += x1; x1 = (x1 << (r)) | (x1 >> (32 - (r))); x1 ^= x0; }
  TFR(13) TFR(15) TFR(26) TFR(6)   x0 += ks1; x1 += ks2 + 1u;
  TFR(17) TFR(29) TFR(16) TFR(24)  x0 += ks2; x1 += ks0 + 2u;
  TFR(13) TFR(15) TFR(26) TFR(6)   x0 += ks0; x1 += ks1 + 3u;
  TFR(17) TFR(29) TFR(16) TFR(24)  x0 += ks1; x1 += ks2 + 4u;
  TFR(13) TFR(15) TFR(26) TFR(6)   x0 += ks2; x1 += ks0 + 5u;
#undef TFR
}

// XLA ErfInv32 (Giles) polynomial
__device__ __forceinline__ float erfinv_f32(float x) {
  float w = -log1pf(-x * x);
  float p;
  if (w < 5.0f) {
    w -= 2.5f;
    p = 2.81022636e-08f;
    p = fmaf(p, w, 3.43273939e-07f);
    p = fmaf(p, w, -3.5233877e-06f);
    p = fmaf(p, w, -4.39150654e-06f);
    p = fmaf(p, w, 0.00021858087f);
    p = fmaf(p, w, -0.00125372503f);
    p = fmaf(p, w, -0.00417768164f);
    p = fmaf(p, w, 0.246640727f);
    p = fmaf(p, w, 1.50140941f);
  } else {
    w = sqrtf(w) - 3.0f;
    p = -0.000200214257f;
    p = fmaf(p, w, 0.000100950558f);
    p = fmaf(p, w, 0.00134934322f);
    p = fmaf(p, w, -0.00367342844f);
    p = fmaf(p, w, 0.00573950773f);
    p = fmaf(p, w, -0.0076224613f);
    p = fmaf(p, w, 0.00943887047f);
    p = fmaf(p, w, 1.00167406f);
    p = fmaf(p, w, 2.83297682f);
  }
  return p * x;
}

__device__ __forceinline__ unsigned jax_random_bits32(unsigned i) {
  unsigned x0 = 0u, x1 = i;
  threefry2x32_042(x0, x1);
  return x0 ^ x1;
}

__device__ __forceinline__ float jax_normal_from_bits(unsigned bits) {
  float f = __uint_as_float((bits >> 9) | 0x3f800000u) - 1.0f;  // [0,1)
  const float lo = -0.99999994f;                                 // nextafter(-1,0)
  float u = f * 2.0f + lo;
  u = fmaxf(u, lo);
  return 1.4142135623730951f * erfinv_f32(u);
}

// ---------------------------------------------------------------------------
// scan_k (unchanged)
// ---------------------------------------------------------------------------
__global__ __launch_bounds__(1024) void scan_k(const int* __restrict__ deg,
                                               int* __restrict__ offs,
                                               int* __restrict__ cur) {
  __shared__ int wsum[16];
  const int t = threadIdx.x;
  const int base = t * 16;
  int loc[16];
  int s = 0;
#pragma unroll
  for (int i = 0; i < 16; i++) { loc[i] = deg[base + i]; s += loc[i]; }
  const int mysum = s;
  const int lane = t & 63, wid = t >> 6;
#pragma unroll
  for (int off = 1; off < 64; off <<= 1) {
    int v = __shfl_up(s, off, 64);
    if (lane >= off) s += v;
  }
  if (lane == 63) wsum[wid] = s;
  __syncthreads();
  if (t == 0) {
    int r = 0;
#pragma unroll
    for (int i = 0; i < 16; i++) { int v = wsum[i]; wsum[i] = r; r += v; }
  }
  __syncthreads();
  int run = wsum[wid] + s - mysum;
#pragma unroll
  for (int i = 0; i < 16; i++) {
    offs[base + i] = run;
    cur[base + i] = run;
    run += loc[i];
  }
  if (t == 1023) offs[NN] = run;
}

// ---------------------------------------------------------------------------
// FAT kernel 1: blocks [0,1024) = edge_count; [1024,1920) = prep_wfrag.
// Independent tasks, no inter-block ordering assumed.
// Weight prep: slots 0-2: W1[a]; 3-5: W2[a]; 6-8: mu_W1[a]; 9:Wq 10:Wk 11:Wv
// 12:Wo (each 16384) | slot 13 region: mu_W2 fragments (3 x 2048)
// ---------------------------------------------------------------------------
__global__ __launch_bounds__(256) void cp_fused(
    const int* __restrict__ dst, int* __restrict__ deg,
    const float* __restrict__ W1, const float* __restrict__ W2,
    const float* __restrict__ mW1,
    const float* __restrict__ Wq, const float* __restrict__ Wk,
    const float* __restrict__ Wv, const float* __restrict__ Wo,
    const float* __restrict__ mW2,
    unsigned short* __restrict__ F) {
  const int b = blockIdx.x;
  if (b < 1024) {   // ---- edge_count ----
    int e = b * 256 + threadIdx.x;
    if (e < EE) atomicAdd(&deg[dst[e]], 1);
    return;
  }
  // ---- prep_wfrag ----
  const int pb = b - 1024;          // 0..895  (= 14 m-slots x 64 f-tiles)
  const int m = pb >> 6;            // 0..13
  const int f = (pb & 63) * 256 + threadIdx.x;
  if (m == 13) {   // mu_W2: A x 128 x 16
    if (f < 6144) {
      int a = f >> 11;
      int r2 = f & 2047;
      int kt = r2 >> 9;
      int r = r2 & 511;
      int lane = r >> 3, j = r & 7;
      int k = kt * 32 + (lane >> 4) * 8 + j;
      int n = lane & 15;
      F[13 * 16384 + f] = f2bf(mW2[(a * 128 + k) * 16 + n]);
    }
    return;
  }
  const float* W;
  if (m < 3) W = W1 + (long)m * 16384;
  else if (m < 6) W = W2 + (long)(m - 3) * 16384;
  else if (m < 9) W = mW1 + (long)(m - 6) * 16384;
  else W = (m == 9) ? Wq : (m == 10) ? Wk : (m == 11) ? Wv : Wo;
  int tile = f >> 9;
  int kt = tile >> 3, nt = tile & 7;
  int r = f & 511;
  int lane = r >> 3, j = r & 7;
  int k = kt * 32 + (lane >> 4) * 8 + j;
  int n = nt * 16 + (lane & 15);
  F[(long)m * 16384 + f] = f2bf(W[k * 128 + n]);
}

// ---------------------------------------------------------------------------
// FAT kernel 2: blocks [0,1024) = edge_fill; [1024,1792) = mlp_fused.
// edge_fill depends only on scan_k; mlp depends only on prep (both done).
// mlp (R6-verified): h = relu(x@W1+b1)@W2 + b2, per a. 128-row tiles.
// ---------------------------------------------------------------------------
#define GXSTR 136
__global__ __launch_bounds__(256, 4) void fm_fused(
    const int* __restrict__ dst, const int* __restrict__ srcv,
    int* __restrict__ cur, int* __restrict__ csr,
    const float* __restrict__ X,
    const unsigned short* __restrict__ WF1, const float* __restrict__ b1,
    const unsigned short* __restrict__ WF2, const float* __restrict__ b2,
    unsigned short* __restrict__ H) {
  __shared__ __align__(16) unsigned short As[128 * GXSTR];
  const int blk = blockIdx.x;
  const int tid = threadIdx.x;
  if (blk < 1024) {   // ---- edge_fill ----
    int e = blk * 256 + tid;
    if (e < EE) {
      int d = dst[e];
      int p = atomicAdd(&cur[d], 1);
      csr[p] = srcv[e];
    }
    return;
  }
  // ---- mlp_fused (R6 form) ----
  const int pb = blk - 1024;        // 0..767
  const int a = pb >> 8;            // 0..2
  const long m0 = (long)(pb & 255) * 128;
  const unsigned short* Wp1 = WF1 + (long)a * 16384;
  const unsigned short* Wp2 = WF2 + (long)a * 16384;

  // stage x tile fp32 -> bf16 (HW packed convert)
#pragma unroll
  for (int p = 0; p < 8; p++) {
    int c = tid + p * 256;
    int row = c >> 4, c8 = (c & 15) * 8;
    float4 v1 = *(const float4*)(X + (m0 + row) * 128 + c8);
    float4 v2 = *(const float4*)(X + (m0 + row) * 128 + c8 + 4);
    uint4 o = make_uint4(pk_bf16(v1.x, v1.y), pk_bf16(v1.z, v1.w),
                         pk_bf16(v2.x, v2.y), pk_bf16(v2.z, v2.w));
    *(uint4*)(&As[row * GXSTR + c8]) = o;
  }
  __syncthreads();

  const int w = tid >> 6, l = tid & 63, lr = l & 15, lg = l >> 4;

  v4f acc[8][2];
#pragma unroll
  for (int mt = 0; mt < 8; mt++) {
    acc[mt][0] = (v4f){0.f, 0.f, 0.f, 0.f};
    acc[mt][1] = (v4f){0.f, 0.f, 0.f, 0.f};
  }
  // phase 1: t1 = x @ W1
#pragma unroll
  for (int kt = 0; kt < 4; kt++) {
    short8 bfr[2];
#pragma unroll
    for (int ntl = 0; ntl < 2; ntl++)
      bfr[ntl] = *(const short8*)(Wp1 + (long)(kt * 8 + 2 * w + ntl) * 512 + l * 8);
#pragma unroll
    for (int mt = 0; mt < 8; mt++) {
      short8 af = *(const short8*)(&As[(mt * 16 + lr) * GXSTR + kt * 32 + lg * 8]);
      acc[mt][0] = __builtin_amdgcn_mfma_f32_16x16x32_bf16(af, bfr[0], acc[mt][0], 0, 0, 0);
      acc[mt][1] = __builtin_amdgcn_mfma_f32_16x16x32_bf16(af, bfr[1], acc[mt][1], 0, 0, 0);
    }
  }
  __syncthreads();   // all As (x) reads done

  // write t1 = relu(acc + b1) back into As
  {
    float bv[2] = {b1[a * 128 + 32 * w + lr], b1[a * 128 + 32 * w + 16 + lr]};
#pragma unroll
    for (int mt = 0; mt < 8; mt++)
#pragma unroll
      for (int ntl = 0; ntl < 2; ntl++)
#pragma unroll
        for (int i = 0; i < 4; i++) {
          int row = mt * 16 + lg * 4 + i;
          int col = 32 * w + ntl * 16 + lr;
          As[row * GXSTR + col] = f2bf(fmaxf(acc[mt][ntl][i] + bv[ntl], 0.0f));
        }
  }
  __syncthreads();

  // phase 2: h = t1 @ W2 + b2
#pragma unroll
  for (int mt = 0; mt < 8; mt++) {
    acc[mt][0] = (v4f){0.f, 0.f, 0.f, 0.f};
    acc[mt][1] = (v4f){0.f, 0.f, 0.f, 0.f};
  }
#pragma unroll
  for (int kt = 0; kt < 4; kt++) {
    short8 bfr[2];
#pragma unroll
    for (int ntl = 0; ntl < 2; ntl++)
      bfr[ntl] = *(const short8*)(Wp2 + (long)(kt * 8 + 2 * w + ntl) * 512 + l * 8);
#pragma unroll
    for (int mt = 0; mt < 8; mt++) {
      short8 af = *(const short8*)(&As[(mt * 16 + lr) * GXSTR + kt * 32 + lg * 8]);
      acc[mt][0] = __builtin_amdgcn_mfma_f32_16x16x32_bf16(af, bfr[0], acc[mt][0], 0, 0, 0);
      acc[mt][1] = __builtin_amdgcn_mfma_f32_16x16x32_bf16(af, bfr[1], acc[mt][1], 0, 0, 0);
    }
  }
  {
    float bv[2] = {b2[a * 128 + 32 * w + lr], b2[a * 128 + 32 * w + 16 + lr]};
#pragma unroll
    for (int mt = 0; mt < 8; mt++)
#pragma unroll
      for (int ntl = 0; ntl < 2; ntl++)
#pragma unroll
        for (int i = 0; i < 4; i++) {
          long row = m0 + mt * 16 + lg * 4 + i;
          int col = 32 * w + ntl * 16 + lr;
          H[row * 384 + a * 128 + col] = f2bf(acc[mt][ntl][i] + bv[ntl]);
        }
  }
}

// ---------------------------------------------------------------------------
// Mega-fused (R6-verified, 90.5us): gather + attention + mu-MLP + noise/logp.
// Gather: depth-4 rolling buffers, preloaded indices, ds_swizzle broadcast,
// packed f32x2 accumulators. launch_bounds(256,3): only spill-free config.
// ---------------------------------------------------------------------------
#define XSTR 136
#define QSTR 34
__global__ __launch_bounds__(256, 3) void attn_mega(
    const unsigned short* __restrict__ H, const int* __restrict__ offs,
    const int* __restrict__ csr,
    const unsigned short* __restrict__ WF,
    const float* __restrict__ bq, const float* __restrict__ bk,
    const float* __restrict__ bv, const float* __restrict__ bo,
    const unsigned short* __restrict__ WM1, const float* __restrict__ mb1,
    const unsigned short* __restrict__ WM2, const float* __restrict__ mb2,
    float* __restrict__ out0, float* __restrict__ out1) {
  __shared__ __align__(16) unsigned short xS[48 * XSTR];
  __shared__ __align__(16) unsigned short kS[4 * 48 * QSTR];
  __shared__ __align__(16) unsigned short vS[4 * 48 * QSTR];
  __shared__ float lpS[48];

  const int tid = threadIdx.x;
  const long node0 = (long)blockIdx.x * 16;

  // ---- phase 0: gather + segment-sum agg for 16 nodes directly into xS ----
  {
    const int bt = (int)(node0 >> 14);           // batch
    const int nbase = (int)(node0 & (NN - 1));
    const int nd = tid >> 4;                     // 0..15 local node
    const int sub = tid & 15;                    // 0..15 col group (24 bf16)
    const int n = nbase + nd;
    const int e0 = offs[n], e1 = offs[n + 1];
    const int cnt = e1 - e0;
    const unsigned short* hb = H + (long)bt * NN * 384 + sub * 24;
    f32x2 acc12[12];
#pragma unroll
    for (int i = 0; i < 12; i++) acc12[i] = (f32x2){0.f, 0.f};

    // preload ALL indices (4 chunks of 16 edges); latency paid once, together
    int i0, i1, i2, i3;
    { int a_ = e0 + sub;      a_ = (a_ < EE) ? a_ : (EE - 1); i0 = csr[a_]; }
    { int a_ = e0 + 16 + sub; a_ = (a_ < EE) ? a_ : (EE - 1); i1 = csr[a_]; }
    { int a_ = e0 + 32 + sub; a_ = (a_ < EE) ? a_ : (EE - 1); i2 = csr[a_]; }
    { int a_ = e0 + 48 + sub; a_ = (a_ < EE) ? a_ : (EE - 1); i3 = csr[a_]; }

    // packed accumulate: 2 unpacks + 1 v_pk_add_f32 per bf16 pair
#define ACC8(bp, u)                                                     \
    { acc12[bp+0] += (f32x2){bflo(u.x), bfhi(u.x)};                     \
      acc12[bp+1] += (f32x2){bflo(u.y), bfhi(u.y)};                     \
      acc12[bp+2] += (f32x2){bflo(u.z), bfhi(u.z)};                     \
      acc12[bp+3] += (f32x2){bflo(u.w), bfhi(u.w)}; }
#define GACC(BUF, KK)                                                   \
    if ((KK) < cnt) { ACC8(0, BUF##0) ACC8(4, BUF##1) ACC8(8, BUF##2) }
#define ROWLD(BUF, SPTR)                                                \
    { const unsigned short* p_ = hb + (long)(SPTR) * 384;               \
      BUF##0 = *(const uint4*)(p_);                                     \
      BUF##1 = *(const uint4*)(p_ + 8);                                 \
      BUF##2 = *(const uint4*)(p_ + 16); }
    // ds_swizzle BitMode (k<<5)|16: new_lane = (lane & 16) | k within each
    // 32-half -> broadcast slot k to its 16-lane group (HW-verified R3).
#define SWZ(reg, k) __builtin_amdgcn_ds_swizzle(reg, ((k) << 5) | 16)
#define IDXG(reg, k, e) (((e) < cnt) ? SWZ(reg, k) : 0)
#define BLOCK16(b, ic, in)                                              \
    GACC(A, (b)+0)  ROWLD(A, IDXG(ic, 4,  (b)+4))                       \
    GACC(B, (b)+1)  ROWLD(B, IDXG(ic, 5,  (b)+5))                       \
    GACC(C, (b)+2)  ROWLD(C, IDXG(ic, 6,  (b)+6))                       \
    GACC(D, (b)+3)  ROWLD(D, IDXG(ic, 7,  (b)+7))                       \
    GACC(A, (b)+4)  ROWLD(A, IDXG(ic, 8,  (b)+8))                       \
    GACC(B, (b)+5)  ROWLD(B, IDXG(ic, 9,  (b)+9))                       \
    GACC(C, (b)+6)  ROWLD(C, IDXG(ic, 10, (b)+10))                      \
    GACC(D, (b)+7)  ROWLD(D, IDXG(ic, 11, (b)+11))                      \
    GACC(A, (b)+8)  ROWLD(A, IDXG(ic, 12, (b)+12))                      \
    GACC(B, (b)+9)  ROWLD(B, IDXG(ic, 13, (b)+13))                      \
    GACC(C, (b)+10) ROWLD(C, IDXG(ic, 14, (b)+14))                      \
    GACC(D, (b)+11) ROWLD(D, IDXG(ic, 15, (b)+15))                      \
    GACC(A, (b)+12) ROWLD(A, IDXG(in, 0,  (b)+16))                      \
    GACC(B, (b)+13) ROWLD(B, IDXG(in, 1,  (b)+17))                      \
    GACC(C, (b)+14) ROWLD(C, IDXG(in, 2,  (b)+18))                      \
    GACC(D, (b)+15) ROWLD(D, IDXG(in, 3,  (b)+19))

    uint4 A0, A1, A2, B0, B1, B2, C0, C1, C2, D0, D1, D2;
    {
      int t0 = IDXG(i0, 0, 0), t1 = IDXG(i0, 1, 1);
      int t2 = IDXG(i0, 2, 2), t3 = IDXG(i0, 3, 3);
      ROWLD(A, t0) ROWLD(B, t1) ROWLD(C, t2) ROWLD(D, t3)
    }
    BLOCK16(0, i0, i1)
    if (cnt > 16) {
      BLOCK16(16, i1, i2)
      if (cnt > 32) {
        BLOCK16(32, i2, i3)
        if (cnt > 48) {
          BLOCK16(48, i3, i3)
        }
      }
    }
    if (cnt > 64) {
      for (int e = 64; e < cnt; e++) {
        int s0 = csr[e0 + e];
        const unsigned short* p0 = hb + (long)s0 * 384;
        uint4 F0 = *(const uint4*)(p0);
        uint4 F1 = *(const uint4*)(p0 + 8);
        uint4 F2 = *(const uint4*)(p0 + 16);
        ACC8(0, F0) ACC8(4, F1) ACC8(8, F2)
      }
    }
#undef BLOCK16
#undef IDXG
#undef SWZ
#undef ROWLD
#undef GACC
#undef ACC8
    // write agg -> xS rows (3*nd + a), packed pairs (pairs never cross a)
#pragma unroll
    for (int jj = 0; jj < 12; jj++) {
      int g = sub * 24 + 2 * jj;
      int a_ = g >> 7;
      int c = g & 127;
      *(unsigned*)&xS[(3 * nd + a_) * XSTR + c] =
          pk_bf16(acc12[jj].x, acc12[jj].y);
    }
  }
  __syncthreads();

  const int w = tid >> 6;
  const int l = tid & 63;
  const int lr = l & 15;
  const int lg = l >> 4;
  const unsigned short* WQ = WF;
  const unsigned short* WK = WF + 16384;
  const unsigned short* WV = WF + 32768;
  const unsigned short* WO = WF + 49152;

  // ---- phase 1: QKV projections ----
  v4f accq[3][2], acck[3][2], accv[3][2];
#pragma unroll
  for (int mt = 0; mt < 3; mt++)
#pragma unroll
    for (int n = 0; n < 2; n++) {
      accq[mt][n] = (v4f){0.f, 0.f, 0.f, 0.f};
      acck[mt][n] = (v4f){0.f, 0.f, 0.f, 0.f};
      accv[mt][n] = (v4f){0.f, 0.f, 0.f, 0.f};
    }
#pragma unroll
  for (int kt = 0; kt < 4; kt++) {
    short8 af[3];
#pragma unroll
    for (int mt = 0; mt < 3; mt++)
      af[mt] = *(const short8*)&xS[(mt * 16 + lr) * XSTR + kt * 32 + lg * 8];
#pragma unroll
    for (int ntl = 0; ntl < 2; ntl++) {
      long tf = (long)(kt * 8 + 2 * w + ntl) * 512 + l * 8;
      short8 b0 = *(const short8*)&WQ[tf];
      short8 b1 = *(const short8*)&WK[tf];
      short8 b2 = *(const short8*)&WV[tf];
#pragma unroll
      for (int mt = 0; mt < 3; mt++) {
        accq[mt][ntl] = __builtin_amdgcn_mfma_f32_16x16x32_bf16(af[mt], b0, accq[mt][ntl], 0, 0, 0);
        acck[mt][ntl] = __builtin_amdgcn_mfma_f32_16x16x32_bf16(af[mt], b1, acck[mt][ntl], 0, 0, 0);
        accv[mt][ntl] = __builtin_amdgcn_mfma_f32_16x16x32_bf16(af[mt], b2, accv[mt][ntl], 0, 0, 0);
      }
    }
  }
  __syncthreads();   // all waves' xS (agg) MFMA reads complete

  // residual pre-read (per-wave own head cols of xS), THEN write Q over them
  float resv[3][2][4];
#pragma unroll
  for (int mt = 0; mt < 3; mt++)
#pragma unroll
    for (int ntl = 0; ntl < 2; ntl++)
#pragma unroll
      for (int i = 0; i < 4; i++)
        resv[mt][ntl][i] =
            bf2f(xS[(mt * 16 + lg * 4 + i) * XSTR + 32 * w + ntl * 16 + lr]);

  {
    const float scale = 0.17677669529663687f;  // 1/sqrt(32)
    unsigned short* kw = &kS[w * 48 * QSTR];
    unsigned short* vw = &vS[w * 48 * QSTR];
    float bqv[2] = {bq[32 * w + lr], bq[32 * w + 16 + lr]};
    float bkv[2] = {bk[32 * w + lr], bk[32 * w + 16 + lr]};
    float bvv[2] = {bv[32 * w + lr], bv[32 * w + 16 + lr]};
#pragma unroll
    for (int mt = 0; mt < 3; mt++)
#pragma unroll
      for (int ntl = 0; ntl < 2; ntl++)
#pragma unroll
        for (int i = 0; i < 4; i++) {
          int row = mt * 16 + lg * 4 + i;
          int col = ntl * 16 + lr;
          xS[row * XSTR + 32 * w + col] = f2bf((accq[mt][ntl][i] + bqv[ntl]) * scale);
          kw[row * QSTR + col] = f2bf(acck[mt][ntl][i] + bkv[ntl]);
          vw[row * QSTR + col] = f2bf(accv[mt][ntl][i] + bvv[ntl]);
        }
  }
  __syncthreads();

  // ---- phase 2: attention; lane l<48 owns (nd=l/3, aq=l%3) of head w.
  // O overwrites lane's own Q row in xS — race-free.
  if (l < 48) {
    int aq = l % 3;
    int ndr = l - aq;
    const unsigned* qr = (const unsigned*)&xS[l * XSTR + 32 * w];
    const unsigned* kr0 = (const unsigned*)&kS[(w * 48 + ndr) * QSTR];
    const unsigned* kr1 = (const unsigned*)&kS[(w * 48 + ndr + 1) * QSTR];
    const unsigned* kr2 = (const unsigned*)&kS[(w * 48 + ndr + 2) * QSTR];
    float s0 = 0.f, s1 = 0.f, s2 = 0.f;
#pragma unroll
    for (int j = 0; j < 16; j++) {
      unsigned uq = qr[j], u0 = kr0[j], u1 = kr1[j], u2 = kr2[j];
      float qa = bflo(uq), qb = bfhi(uq);
      s0 = fmaf(qa, bflo(u0), fmaf(qb, bfhi(u0), s0));
      s1 = fmaf(qa, bflo(u1), fmaf(qb, bfhi(u1), s1));
      s2 = fmaf(qa, bflo(u2), fmaf(qb, bfhi(u2), s2));
    }
    float mx = fmaxf(s0, fmaxf(s1, s2));
    float e0 = expf(s0 - mx), e1 = expf(s1 - mx), e2 = expf(s2 - mx);
    float inv = 1.0f / (e0 + e1 + e2);
    e0 *= inv; e1 *= inv; e2 *= inv;
    const unsigned* vr0 = (const unsigned*)&vS[(w * 48 + ndr) * QSTR];
    const unsigned* vr1 = (const unsigned*)&vS[(w * 48 + ndr + 1) * QSTR];
    const unsigned* vr2 = (const unsigned*)&vS[(w * 48 + ndr + 2) * QSTR];
    unsigned ov[16];
#pragma unroll
    for (int j = 0; j < 16; j++) {
      unsigned u0 = vr0[j], u1 = vr1[j], u2 = vr2[j];
      float oa = fmaf(e0, bflo(u0), fmaf(e1, bflo(u1), e2 * bflo(u2)));
      float ob = fmaf(e0, bfhi(u0), fmaf(e1, bfhi(u1), e2 * bfhi(u2)));
      ov[j] = pk_bf16(oa, ob);
    }
    uint4* orow = (uint4*)&xS[l * XSTR + 32 * w];
    orow[0] = make_uint4(ov[0], ov[1], ov[2], ov[3]);
    orow[1] = make_uint4(ov[4], ov[5], ov[6], ov[7]);
    orow[2] = make_uint4(ov[8], ov[9], ov[10], ov[11]);
    orow[3] = make_uint4(ov[12], ov[13], ov[14], ov[15]);
  }
  __syncthreads();

  // ---- phase 3: hI = agg + O @ Wo + bo ----
  v4f acco[3][2];
#pragma unroll
  for (int mt = 0; mt < 3; mt++)
#pragma unroll
    for (int n = 0; n < 2; n++) acco[mt][n] = (v4f){0.f, 0.f, 0.f, 0.f};
#pragma unroll
  for (int kt = 0; kt < 4; kt++) {
    short8 af[3];
#pragma unroll
    for (int mt = 0; mt < 3; mt++)
      af[mt] = *(const short8*)&xS[(mt * 16 + lr) * XSTR + kt * 32 + lg * 8];
#pragma unroll
    for (int ntl = 0; ntl < 2; ntl++) {
      long tf = (long)(kt * 8 + 2 * w + ntl) * 512 + l * 8;
      short8 b = *(const short8*)&WO[tf];
#pragma unroll
      for (int mt = 0; mt < 3; mt++)
        acco[mt][ntl] = __builtin_amdgcn_mfma_f32_16x16x32_bf16(af[mt], b, acco[mt][ntl], 0, 0, 0);
    }
  }
  __syncthreads();   // all O reads of xS done

  // write hI into xS, a-major rows: row' = a*16 + nd  (orig row = 3*nd + a)
  {
    float bov[2] = {bo[32 * w + lr], bo[32 * w + 16 + lr]};
#pragma unroll
    for (int mt = 0; mt < 3; mt++)
#pragma unroll
      for (int ntl = 0; ntl < 2; ntl++)
#pragma unroll
        for (int i = 0; i < 4; i++) {
          int row = mt * 16 + lg * 4 + i;
          int nd = row / 3, a_ = row - nd * 3;
          int gcol = 32 * w + ntl * 16 + lr;
          xS[(a_ * 16 + nd) * XSTR + gcol] =
              f2bf(acco[mt][ntl][i] + bov[ntl] + resv[mt][ntl][i]);
        }
  }
  __syncthreads();

  // ---- phase 4: m = relu(hI @ mu_W1[a] + mb1[a]); tile mt == a ----
  v4f accm[3][2];
#pragma unroll
  for (int mt = 0; mt < 3; mt++)
#pragma unroll
    for (int n = 0; n < 2; n++) accm[mt][n] = (v4f){0.f, 0.f, 0.f, 0.f};
#pragma unroll
  for (int kt = 0; kt < 4; kt++) {
#pragma unroll
    for (int mt = 0; mt < 3; mt++) {
      short8 af = *(const short8*)&xS[(mt * 16 + lr) * XSTR + kt * 32 + lg * 8];
#pragma unroll
      for (int ntl = 0; ntl < 2; ntl++) {
        short8 b = *(const short8*)(WM1 + (long)mt * 16384 +
                                    (long)(kt * 8 + 2 * w + ntl) * 512 + l * 8);
        accm[mt][ntl] = __builtin_amdgcn_mfma_f32_16x16x32_bf16(af, b, accm[mt][ntl], 0, 0, 0);
      }
    }
  }
  __syncthreads();   // all hI reads done

  // write m into xS (already a-major: tile mt rows = a*16 + nd)
#pragma unroll
  for (int mt = 0; mt < 3; mt++)
#pragma unroll
    for (int ntl = 0; ntl < 2; ntl++) {
      int col = 32 * w + ntl * 16 + lr;
      float bias = mb1[mt * 128 + col];
#pragma unroll
      for (int i = 0; i < 4; i++) {
        int rowp = mt * 16 + lg * 4 + i;
        xS[rowp * XSTR + col] = f2bf(fmaxf(accm[mt][ntl][i] + bias, 0.0f));
      }
    }
  __syncthreads();

  // ---- phase 5: mu = m @ mu_W2[a] + mb2[a]; wave w handles a = w (w<3) ----
  if (w < 3) {
    v4f accu = (v4f){0.f, 0.f, 0.f, 0.f};
#pragma unroll
    for (int kt = 0; kt < 4; kt++) {
      short8 af = *(const short8*)&xS[(w * 16 + lr) * XSTR + kt * 32 + lg * 8];
      short8 b = *(const short8*)(WM2 + w * 2048 + kt * 512 + l * 8);
      accu = __builtin_amdgcn_mfma_f32_16x16x32_bf16(af, b, accu, 0, 0, 0);
    }
    float bias = mb2[w * 16 + lr];
#pragma unroll
    for (int i = 0; i < 4; i++) {
      int nd = lg * 4 + i;
      float mu = accu[i] + bias;
      unsigned gidx = (unsigned)((node0 + nd) * 48 + w * 16 + lr);
      unsigned bits = jax_random_bits32(gidx);
      float noise = jax_normal_from_bits(bits);
      float sample = mu + noise;
      float lp = -0.9189385332046727f - 0.5f * noise * noise;
      lp += __shfl_xor(lp, 1, 64);
      lp += __shfl_xor(lp, 2, 64);
      lp += __shfl_xor(lp, 4, 64);
      lp += __shfl_xor(lp, 8, 64);
      if (lr == 0) lpS[w * 16 + nd] = lp;
      float res;
      if (w == 0) {
        float th = tanhf(sample);
        float mx = th;
        mx = fmaxf(mx, __shfl_xor(mx, 1, 64));
        mx = fmaxf(mx, __shfl_xor(mx, 2, 64));
        mx = fmaxf(mx, __shfl_xor(mx, 4, 64));
        mx = fmaxf(mx, __shfl_xor(mx, 8, 64));
        float ex = expf(th - mx);
        float ss = ex;
        ss += __shfl_xor(ss, 1, 64);
        ss += __shfl_xor(ss, 2, 64);
        ss += __shfl_xor(ss, 4, 64);
        ss += __shfl_xor(ss, 8, 64);
        res = ex / ss;
      } else if (w == 1) {
        res = 1.0f / (1.0f + expf(-sample));
      } else {
        res = tanhf(sample);
      }
      out0[gidx] = res;
    }
  }
  __syncthreads();
  if (tid < 16)
    out1[node0 + tid] = lpS[tid] + lpS[16 + tid] + lpS[32 + tid];
}

// ---------------------------------------------------------------------------
extern "C" void kernel_launch(void* const* d_in, const int* in_sizes, int n_in,
                              void* d_out, int out_size, void* d_ws, size_t ws_size,
                              hipStream_t stream) {
  const float* x = (const float*)d_in[0];
  const int* ei = (const int*)d_in[1];
  const float* W1 = (const float*)d_in[2];
  const float* b1 = (const float*)d_in[3];
  const float* W2 = (const float*)d_in[4];
  const float* b2 = (const float*)d_in[5];
  const float* Wq = (const float*)d_in[6];
  const float* bq = (const float*)d_in[7];
  const float* Wk = (const float*)d_in[8];
  const float* bk = (const float*)d_in[9];
  const float* Wv = (const float*)d_in[10];
  const float* bv = (const float*)d_in[11];
  const float* Wo = (const float*)d_in[12];
  const float* bo = (const float*)d_in[13];
  const float* mW1 = (const float*)d_in[14];
  const float* mb1 = (const float*)d_in[15];
  const float* mW2 = (const float*)d_in[16];
  const float* mb2 = (const float*)d_in[17];
  (void)in_sizes; (void)n_in; (void)out_size; (void)ws_size;

  unsigned short* HB = (unsigned short*)d_ws;      // 12,582,912 (h bf16)
  int* deg = (int*)(HB + 12582912);                // 16384
  int* offs = deg + NN;                            // 16385
  int* cur = offs + (NN + 1);                      // 16384
  int* csr = cur + NN;                             // 262144
  unsigned short* wfrag = (unsigned short*)(((uintptr_t)(csr + EE) + 15) & ~(uintptr_t)15);
  unsigned short* w2frag = wfrag + 13 * 16384;     // 3*2048

  const int* dst = ei;
  const int* srcv = ei + EE;

  float* out0 = (float*)d_out;
  float* out1 = out0 + TOT_NOISE;

  hipMemsetAsync(deg, 0, NN * sizeof(int), stream);
  // fat 1: edge_count (1024 blocks) || prep_wfrag (896 blocks)
  cp_fused<<<1920, 256, 0, stream>>>(dst, deg, W1, W2, mW1, Wq, Wk, Wv, Wo,
                                     mW2, wfrag);
  scan_k<<<1, 1024, 0, stream>>>(deg, offs, cur);
  // fat 2: edge_fill (1024 blocks) || mlp_fused (768 blocks)
  fm_fused<<<1792, 256, 0, stream>>>(dst, srcv, cur, csr,
                                     x, wfrag, b1, wfrag + 3 * 16384, b2, HB);
  // gather + attention + hI + mu-MLP + noise/logp (mega-fused)
  attn_mega<<<BNODES / 16, 256, 0, stream>>>(HB, offs, csr,
                                             wfrag + 9 * 16384, bq, bk, bv, bo,
                                             wfrag + 6 * 16384, mb1, w2frag, mb2,
                                             out0, out1);
}